// Round 22
// baseline (1241.034 us; speedup 1.0000x reference)
//
#include <hip/hip_runtime.h>

#define DEV_INLINE __device__ __forceinline__
typedef unsigned long long ull;
typedef unsigned int u32;
typedef unsigned short u16;
typedef __attribute__((ext_vector_type(8))) short short8v;   // 8 bf16 (4 VGPRs)
typedef __attribute__((ext_vector_type(4))) float f32x4;

// ---------------- split-bf16 helpers ----------------
DEV_INLINE u32 rne16(float f){
  u32 u = __float_as_uint(f);
  return (u + 0x7fffu + ((u>>16)&1u)) >> 16;
}
DEV_INLINE u32 packsplit(float a){
  u32 h = rne16(a);
  float hf = __uint_as_float(h<<16);
  u32 l = rne16(a - hf);
  return h | (l<<16);
}
DEV_INLINE float unpackv(u32 w){
  return __uint_as_float(w<<16) + __uint_as_float(w & 0xffff0000u);
}

// ---------------- prep: transposes + all weight packing, one dispatch ----------------
// NOTE: decT is now produced PADDED to 28 floats/row (b128-aligned rows) for
// the fused dec phase in stage_a1.
__global__ void prep_all(const float* __restrict__ enc_w, float* __restrict__ encTg,
                         const float* __restrict__ dec_w, float* __restrict__ decT28,
                         const float* __restrict__ red_w, float* __restrict__ redT,
                         const float* __restrict__ fc_w,  float* __restrict__ fcT,
                         const float* __restrict__ c1w, u16* __restrict__ W1h, u16* __restrict__ W1l,
                         const float* __restrict__ c2w, u16* __restrict__ W2h, u16* __restrict__ W2l,
                         const float* __restrict__ c3w, u16* __restrict__ W3h, u16* __restrict__ W3l,
                         const float* __restrict__ c4w, u16* __restrict__ W4h, u16* __restrict__ W4l,
                         const float* __restrict__ c5w, u16* __restrict__ W5h, u16* __restrict__ W5l)
{
  const int b = blockIdx.x, t = threadIdx.x;
  auto t2 = [&](const float* A, float* AT, int R, int C, int base){
    int i = (b-base)*256 + t; if (i < R*C){ int r=i%R, c=i/R; AT[i] = A[r*C+c]; }
  };
  auto pk = [&](const float* W, u16* wh, u16* wl, int CIN, int COUT, int base){
    int TPI = CIN/32, KS = 9*TPI;
    int tid = (b-base)*256 + t;
    if (tid >= KS*COUT) return;
    int co = tid % COUT, ks = tid / COUT;
    int tap = ks/TPI, cib = (ks - tap*TPI)*32;
    u16* dh = wh + (size_t)tid*32;
    u16* dl = wl + (size_t)tid*32;
    for (int kl=0; kl<32; ++kl){
      float w = W[((size_t)(co*CIN + cib + kl))*9 + tap];
      u32 h = rne16(w);
      float hf = __uint_as_float(h<<16);
      u32 l = rne16(w - hf);
      dh[kl] = (u16)h; dl[kl] = (u16)l;
    }
  };
  if      (b < 27){
    // dec: W[27][256] -> decT28[idx][28] (row o = W[o][idx]), padded rows
    int i = b*256 + t;   // i = o*256 + idx ordering over 27*256
    if (i < 27*256){ int o = i/256, idx = i - o*256; decT28[idx*28 + o] = dec_w[i]; }
    // also enc in same range? keep enc separate below
  }
  if      (b >= 27 && b < 54)  t2(enc_w, encTg, 256, 27, 27);
  else if (b >= 54 && b < 118) t2(red_w, redT, 64, 256, 54);
  else if (b >= 118 && b < 518) t2(fc_w,  fcT, 100, 1024, 118);
  else if (b >= 518 && b < 525) pk(c1w, W1h, W1l, 64, 96, 518);
  else if (b >= 525 && b < 539) pk(c2w, W2h, W2l, 96, 128, 525);
  else if (b >= 539 && b < 562) pk(c3w, W3h, W3l, 128, 160, 539);
  else if (b >= 562 && b < 596) pk(c4w, W4h, W4l, 160, 192, 562);
  else if (b >= 596)            pk(c5w, W5h, W5l, 192, 256, 596);
}

// ---------------- A1: enc conv + topk (DUAL chains) + FUSED dec/sigmoid/aux ----------------
// r15 core (52 VGPR, occ 43%) + a2's dec phase fused in the tail: survivors are
// already in LDS (svf/svi), so a2's 37MB svg re-read + dispatch disappear.
// LDS 6.1K -> 35.8K (still 4 blocks/CU). Spill tripwire: WRITE_SIZE >> 49MB.
__global__ __launch_bounds__(256, 4) void stage_a1(
    const float* __restrict__ encTg, const float* __restrict__ enc_b,
    const float* __restrict__ x, const int* __restrict__ kp,
    const float* __restrict__ decT28, const float* __restrict__ dec_b,
    float* __restrict__ svg_v, unsigned char* __restrict__ svg_i,
    float* __restrict__ auxp)
{
  __shared__ float  rows[9*32];              // 1152 B
  __shared__ float  svf[30*33];              // 3960 B
  __shared__ unsigned char svi[30*33];       // 990 B
  __shared__ __align__(16) float decl[256*28]; // 28672 B
  __shared__ float redbuf[256];              // 1024 B

  const int t = threadIdx.x, oh = blockIdx.x, b = blockIdx.y;
  const int k = __builtin_amdgcn_readfirstlane(*kp);
  const int wid = t>>6, lane = t&63;
  const float4* encW4 = (const float4*)encTg;

  for (int e=t; e<288; e+=256){
    int ci = e/96, r = (e/32)%3, xx = e&31;
    rows[(ci*3+r)*32+xx] = x[((b*3+ci)*32 + (oh+r))*32 + xx];
  }
  for (int e=t; e<990; e+=256){ svf[e]=0.f; svi[e]=0; }
  for (int e=t; e<7168; e+=256) decl[e] = decT28[e];
  __syncthreads();

  const float4 eb = ((const float4*)enc_b)[lane];

  auto cnt4 = [&](unsigned c, unsigned u0, unsigned u1, unsigned u2, unsigned u3)->int{
    return __popcll(__ballot(u0>=c)) + __popcll(__ballot(u1>=c))
         + __popcll(__ballot(u2>=c)) + __popcll(__ballot(u3>=c));
  };
  auto compact = [&](float v0,float v1,float v2,float v3,
                     unsigned u0,unsigned u1,unsigned u2,unsigned u3,
                     unsigned th, int pi){
    bool k0=u0>=th, k1=u1>=th, k2=u2>=th, k3=u3>=th;
    ull B0=__ballot(k0), B1=__ballot(k1), B2=__ballot(k2), B3=__ballot(k3);
    ull below=(1ull<<lane)-1ull;
    int n0=__popcll(B0), n1=__popcll(B1), n2=__popcll(B2);
    int o0=__popcll(B0&below);
    int o1=n0+__popcll(B1&below);
    int o2=n0+n1+__popcll(B2&below);
    int o3=n0+n1+n2+__popcll(B3&below);
    float* sf = &svf[pi*33]; unsigned char* si = &svi[pi*33];
    if (k0&&o0<32){ sf[o0]=v0; si[o0]=(unsigned char)(4*lane+0); }
    if (k1&&o1<32){ sf[o1]=v1; si[o1]=(unsigned char)(4*lane+1); }
    if (k2&&o2<32){ sf[o2]=v2; si[o2]=(unsigned char)(4*lane+2); }
    if (k3&&o3<32){ sf[o3]=v3; si[o3]=(unsigned char)(4*lane+3); }
  };

  for (int it=0; it<4; ++it){
    const int pr = wid*4 + it;
    if (pr >= 15) break;                 // wave-uniform
    const int ow0 = 2*pr;

    float a0=eb.x,a1=eb.y,a2=eb.z,a3=eb.w;   // pos ow0
    float c0=eb.x,c1=eb.y,c2=eb.z,c3=eb.w;   // pos ow0+1
    #pragma unroll
    for (int ci=0; ci<3; ++ci)
      #pragma unroll
      for (int i=0;i<3;++i){
        const int rbase = (ci*3+i)*32 + ow0;
        float p0 = rows[rbase+0], p1 = rows[rbase+1];
        float p2 = rows[rbase+2], p3 = rows[rbase+3];
        float4 w0 = encW4[(ci*9+i*3+0)*64 + lane];
        float4 w1 = encW4[(ci*9+i*3+1)*64 + lane];
        float4 w2 = encW4[(ci*9+i*3+2)*64 + lane];
        a0=fmaf(w0.x,p0,a0); a1=fmaf(w0.y,p0,a1); a2=fmaf(w0.z,p0,a2); a3=fmaf(w0.w,p0,a3);
        c0=fmaf(w0.x,p1,c0); c1=fmaf(w0.y,p1,c1); c2=fmaf(w0.z,p1,c2); c3=fmaf(w0.w,p1,c3);
        a0=fmaf(w1.x,p1,a0); a1=fmaf(w1.y,p1,a1); a2=fmaf(w1.z,p1,a2); a3=fmaf(w1.w,p1,a3);
        c0=fmaf(w1.x,p2,c0); c1=fmaf(w1.y,p2,c1); c2=fmaf(w1.z,p2,c2); c3=fmaf(w1.w,p2,c3);
        a0=fmaf(w2.x,p2,a0); a1=fmaf(w2.y,p2,a1); a2=fmaf(w2.z,p2,a2); a3=fmaf(w2.w,p2,a3);
        c0=fmaf(w2.x,p3,c0); c1=fmaf(w2.y,p3,c1); c2=fmaf(w2.z,p3,c2); c3=fmaf(w2.w,p3,c3);
      }

    unsigned A0=__float_as_uint(a0)&0x7fffffffu, A1=__float_as_uint(a1)&0x7fffffffu;
    unsigned A2=__float_as_uint(a2)&0x7fffffffu, A3=__float_as_uint(a3)&0x7fffffffu;
    unsigned C0=__float_as_uint(c0)&0x7fffffffu, C1=__float_as_uint(c1)&0x7fffffffu;
    unsigned C2=__float_as_uint(c2)&0x7fffffffu, C3=__float_as_uint(c3)&0x7fffffffu;

    unsigned thA=0, thB=0;
    int dA=0, dB=0;
    for (int bit=30; bit>=0; --bit){
      if (!dA){
        unsigned c = thA | (1u<<bit);
        int n = cnt4(c,A0,A1,A2,A3);
        if (n>=k) thA=c;
        if (n==k) dA=1;
      }
      if (!dB){
        unsigned c = thB | (1u<<bit);
        int n = cnt4(c,C0,C1,C2,C3);
        if (n>=k) thB=c;
        if (n==k) dB=1;
      }
      if (dA & dB) break;
    }

    compact(a0,a1,a2,a3, A0,A1,A2,A3, thA, ow0);
    compact(c0,c1,c2,c3, C0,C1,C2,C3, thB, ow0+1);
  }
  __syncthreads();

  // svg stores (consumed by a3)
  const size_t gbase = (size_t)b*900 + (size_t)oh*30;
  for (int e=t; e<960; e+=256){
    int jj = e/30, pi = e - jj*30;
    svg_v[(size_t)jj*230400 + gbase + pi] = svf[pi*33+jj];
    svg_i[(size_t)jj*230400 + gbase + pi] = svi[pi*33+jj];
  }

  // FUSED dec + sigmoid + aux: unit = (position pi, float4-chunk c), 210 active
  float auxacc = 0.f;
  if (t < 210){
    const int pi = t/7, c = t - (t/7)*7;
    const float4* decl4 = (const float4*)decl;
    float av0=0.f, av1=0.f, av2=0.f, av3=0.f;
    #pragma unroll
    for (int j=0;j<32;++j){
      float v = svf[pi*33+j];
      int idx = (int)svi[pi*33+j];
      float4 w = decl4[idx*7 + c];
      av0 = fmaf(v, w.x, av0); av1 = fmaf(v, w.y, av1);
      av2 = fmaf(v, w.z, av2); av3 = fmaf(v, w.w, av3);
    }
    float av[4] = {av0, av1, av2, av3};
    #pragma unroll
    for (int oj=0;oj<4;++oj){
      int o = c*4 + oj;
      if (o < 27){
        float dacc = av[oj] + dec_b[o];
        float dv = 1.f/(1.f + __expf(-dacc));
        int ci = o/9, r2 = (o - ci*9)/3, c2 = o%3;
        float tg = rows[(ci*3+r2)*32 + pi + c2];
        float df = tg - dv;
        auxacc = fmaf(df, df, auxacc);
      }
    }
  }
  redbuf[t] = auxacc; __syncthreads();
  for (int off=128; off; off>>=1){ if (t<off) redbuf[t]+=redbuf[t+off]; __syncthreads(); }
  if (t==0) auxp[(size_t)b*30 + oh] = redbuf[0];
}

// ---------------- A3: red -> packed x1p [pos][64], float4 gathers + fused bn1 stats ----------------
__global__ __launch_bounds__(256) void stage_a3p2(
    const float* __restrict__ svg_v, const unsigned char* __restrict__ svg_i,
    const float* __restrict__ redT, const float* __restrict__ red_b,
    u32* __restrict__ x1p, float* __restrict__ psum1, float* __restrict__ psq1)
{
  __shared__ __align__(16) float redl[256*68];  // 69632 B, row = 17 float4
  __shared__ u32   obuf[256*65];                // 66560 B
  const int t = threadIdx.x;
  for (int e=t; e<16384; e+=256) redl[(e>>6)*68 + (e&63)] = redT[e];
  __syncthreads();

  const int pos = blockIdx.x*256 + t;

  float v[32]; int a[32];
  #pragma unroll
  for (int j=0;j<32;++j) v[j] = svg_v[(size_t)j*230400 + pos];
  #pragma unroll
  for (int j=0;j<32;++j) a[j] = (int)svg_i[(size_t)j*230400 + pos]*17; // float4-row

  const float4* redl4 = (const float4*)redl;
  #pragma unroll 2
  for (int ocb=0; ocb<16; ++ocb){
    float s0 = red_b[4*ocb+0], s1 = red_b[4*ocb+1];
    float s2 = red_b[4*ocb+2], s3 = red_b[4*ocb+3];
    #pragma unroll
    for (int j=0;j<32;++j){
      float4 w = redl4[a[j] + ocb];
      s0 = fmaf(v[j], w.x, s0); s1 = fmaf(v[j], w.y, s1);
      s2 = fmaf(v[j], w.z, s2); s3 = fmaf(v[j], w.w, s3);
    }
    obuf[t*65 + 4*ocb+0] = packsplit(s0);
    obuf[t*65 + 4*ocb+1] = packsplit(s1);
    obuf[t*65 + 4*ocb+2] = packsplit(s2);
    obuf[t*65 + 4*ocb+3] = packsplit(s3);
  }
  __syncthreads();   // all redl reads + obuf writes complete

  const size_t base = (size_t)blockIdx.x*16384;
  float s = 0.f, q = 0.f;
  for (int e=t; e<16384; e+=256){
    u32 w = obuf[(e>>6)*65 + (e&63)];
    x1p[base + e] = w;
    float vv = unpackv(w);
    s += vv; q = fmaf(vv, vv, q);
  }
  float* ls = redl; float* lq = redl + 256;
  ls[t] = s; lq[t] = q; __syncthreads();
  if (t < 128){ ls[t] += ls[t+128]; lq[t] += lq[t+128]; } __syncthreads();
  if (t < 64){
    psum1[(size_t)blockIdx.x*64 + t] = ls[t] + ls[t+64];
    psq1 [(size_t)blockIdx.x*64 + t] = lq[t] + lq[t+64];
  }
}

// ---------------- bn1 finalize: one block per channel (64 blocks) ----------------
__global__ __launch_bounds__(256) void bn1_final(
    const float* __restrict__ ps, const float* __restrict__ pq,
    const float* __restrict__ g, const float* __restrict__ b2,
    float* __restrict__ sc, float* __restrict__ sh)
{
  __shared__ float ls[256], lq[256];
  const int c = blockIdx.x, t = threadIdx.x;
  float s=0.f, q=0.f;
  for (int i=t; i<900; i+=256){ s += ps[(size_t)i*64+c]; q += pq[(size_t)i*64+c]; }
  ls[t]=s; lq[t]=q; __syncthreads();
  for (int off=128; off; off>>=1){
    if (t<off){ ls[t]+=ls[t+off]; lq[t]+=lq[t+off]; } __syncthreads();
  }
  if (t==0){
    constexpr float inv_n = 1.f/230400.f;
    float m = ls[0]*inv_n;
    float var = fmaf(lq[0], inv_n, -m*m);
    float rs = rsqrtf(var + 1e-5f);
    float scale = g[c]*rs;
    sc[c] = scale;
    sh[c] = fmaf(-m, scale, b2[c]);
  }
}

// ---------------- generic BN finalize: ONE BLOCK PER CHANNEL ----------------
template<int C>
__global__ __launch_bounds__(256) void bn_finalG(
    const float* __restrict__ ps, const float* __restrict__ pq, int G,
    const float* __restrict__ g, const float* __restrict__ b2,
    float* __restrict__ sc, float* __restrict__ sh, float inv_n)
{
  __shared__ float ls[256], lq[256];
  const int c = blockIdx.x, t = threadIdx.x;
  float s=0.f, q=0.f;
  for (int i=t; i<G; i+=256){ s += ps[(size_t)i*C+c]; q += pq[(size_t)i*C+c]; }
  ls[t]=s; lq[t]=q; __syncthreads();
  for (int off=128; off; off>>=1){
    if (t<off){ ls[t]+=ls[t+off]; lq[t]+=lq[t+off]; } __syncthreads();
  }
  if (t==0){
    float m = ls[0]*inv_n;
    float var = fmaf(lq[0], inv_n, -m*m);
    float rs = rsqrtf(var + 1e-5f);
    float scale = g[c]*rs;
    sc[c] = scale;
    sh[c] = fmaf(-m, scale, b2[c]);
  }
}

// ---------------- cvt: in-place packed->packed BN+ReLU ----------------
template<int C>
__global__ void cvt_repack(u32* __restrict__ xp, const float* __restrict__ sc,
                           const float* __restrict__ sh, int total4){
  int i = blockIdx.x*256 + threadIdx.x;
  if (i >= total4) return;
  uint4* p = (uint4*)xp;
  uint4 w = p[i];
  int cb = (i*4) % C;     // C%4==0
  w.x = packsplit(fmaxf(fmaf(unpackv(w.x), sc[cb+0], sh[cb+0]), 0.f));
  w.y = packsplit(fmaxf(fmaf(unpackv(w.y), sc[cb+1], sh[cb+1]), 0.f));
  w.z = packsplit(fmaxf(fmaf(unpackv(w.z), sc[cb+2], sh[cb+2]), 0.f));
  w.w = packsplit(fmaxf(fmaf(unpackv(w.w), sc[cb+3], sh[cb+3]), 0.f));
  p[i] = w;
}

// ---------------- conv via MFMA implicit GEMM, 3x bf16 split + fused BN partial stats ----------------
template<int CIN,int COUT,int HIN,int WIN,int BM,int MW,bool POOL,bool PKOUT>
__global__ __launch_bounds__(256) void conv_mfma(
    const u32* __restrict__ xp, const u16* __restrict__ wh,
    const u16* __restrict__ wl, const float* __restrict__ bias,
    void* __restrict__ y_, float* __restrict__ psC, float* __restrict__ qsC)
{
  constexpr int HC=HIN-2, WC=WIN-2, TPI=CIN/32, KS=9*TPI, NCH=COUT/16;
  const int t = threadIdx.x, wid = t>>6, lane = t&63;
  const int p0 = blockIdx.x*BM;
  const int colg = lane>>4;
  const int col = lane&15;
  float* yf = (float*)y_;
  u32*   yp = (u32*)y_;

  const u32* Aptr[MW];
  #pragma unroll
  for (int m=0;m<MW;++m){
    int l = (wid*MW+m)*16 + col;
    int lc = l < BM ? l : BM-1;
    int p = p0 + lc;
    int b = p/(HC*WC); int rem = p - b*(HC*WC);
    int oh = rem/WC, ow = rem - (rem/WC)*WC;
    Aptr[m] = xp + ((size_t)((b*HIN+oh)*WIN+ow))*CIN + colg*8;
  }
  const size_t wb = (size_t)col*32 + colg*8;

  f32x4 acc[MW][NCH];
  #pragma unroll
  for (int m=0;m<MW;++m)
    #pragma unroll
    for (int nc=0;nc<NCH;++nc) acc[m][nc] = (f32x4){0.f,0.f,0.f,0.f};

  for (int ks=0; ks<KS; ++ks){
    const int tap = ks/TPI, cib = (ks - tap*TPI)*32;
    const int kh = tap/3, kw = tap - kh*3;
    short8v ah[MW], al[MW];
    #pragma unroll
    for (int m=0;m<MW;++m){
      const u32* ap = Aptr[m] + (kh*WIN + kw)*CIN + cib;
      uint4 qa = *(const uint4*)(ap);
      uint4 qb = *(const uint4*)(ap+4);
      ah[m][0]=(short)(qa.x&0xffffu); al[m][0]=(short)(qa.x>>16);
      ah[m][1]=(short)(qa.y&0xffffu); al[m][1]=(short)(qa.y>>16);
      ah[m][2]=(short)(qa.z&0xffffu); al[m][2]=(short)(qa.z>>16);
      ah[m][3]=(short)(qa.w&0xffffu); al[m][3]=(short)(qa.w>>16);
      ah[m][4]=(short)(qb.x&0xffffu); al[m][4]=(short)(qb.x>>16);
      ah[m][5]=(short)(qb.y&0xffffu); al[m][5]=(short)(qb.y>>16);
      ah[m][6]=(short)(qb.z&0xffffu); al[m][6]=(short)(qb.z>>16);
      ah[m][7]=(short)(qb.w&0xffffu); al[m][7]=(short)(qb.w>>16);
    }
    const u16* whp = wh + (size_t)ks*COUT*32 + wb;
    const u16* wlp = wl + (size_t)ks*COUT*32 + wb;
    #pragma unroll
    for (int nc=0;nc<NCH;++nc){
      short8v bh = *(const short8v*)(whp + nc*512);
      short8v bl = *(const short8v*)(wlp + nc*512);
      #pragma unroll
      for (int m=0;m<MW;++m){
        acc[m][nc] = __builtin_amdgcn_mfma_f32_16x16x32_bf16(ah[m], bh, acc[m][nc], 0,0,0);
        acc[m][nc] = __builtin_amdgcn_mfma_f32_16x16x32_bf16(ah[m], bl, acc[m][nc], 0,0,0);
        acc[m][nc] = __builtin_amdgcn_mfma_f32_16x16x32_bf16(al[m], bh, acc[m][nc], 0,0,0);
      }
    }
  }

  if constexpr (!POOL){
    __shared__ float ldsS[4][COUT], ldsQ[4][COUT];
    float sacc[NCH], qacc[NCH];
    #pragma unroll
    for (int nc=0;nc<NCH;++nc){ sacc[nc]=0.f; qacc[nc]=0.f; }
    #pragma unroll
    for (int m=0;m<MW;++m){
      const int lr0 = (wid*MW+m)*16 + colg*4;
      #pragma unroll
      for (int nc=0;nc<NCH;++nc){
        float bv = bias[nc*16+col];
        #pragma unroll
        for (int r=0;r<4;++r)
          if (lr0+r < BM){
            float ov = acc[m][nc][r] + bv;
            float vv;
            if constexpr (PKOUT){
              u32 w = packsplit(ov);
              yp[(size_t)(p0+lr0+r)*COUT + nc*16+col] = w;
              vv = unpackv(w);
            } else {
              yf[(size_t)(p0+lr0+r)*COUT + nc*16+col] = ov;
              vv = ov;
            }
            sacc[nc] += vv; qacc[nc] = fmaf(vv, vv, qacc[nc]);
          }
      }
    }
    #pragma unroll
    for (int nc=0;nc<NCH;++nc){
      float s_ = sacc[nc], q_ = qacc[nc];
      s_ += __shfl_xor(s_, 16); q_ += __shfl_xor(q_, 16);
      s_ += __shfl_xor(s_, 32); q_ += __shfl_xor(q_, 32);
      if (colg == 0){ ldsS[wid][nc*16+col] = s_; ldsQ[wid][nc*16+col] = q_; }
    }
    __syncthreads();
    if (t < COUT){
      psC[(size_t)blockIdx.x*COUT + t] = ldsS[0][t]+ldsS[1][t]+ldsS[2][t]+ldsS[3][t];
      qsC[(size_t)blockIdx.x*COUT + t] = ldsQ[0][t]+ldsQ[1][t]+ldsQ[2][t]+ldsQ[3][t];
    }
  } else {
    constexpr int LDC = COUT+4;
    __shared__ float lds[BM*LDC];
    #pragma unroll
    for (int m=0;m<MW;++m){
      const int lr0 = (wid*MW+m)*16 + colg*4;
      #pragma unroll
      for (int nc=0;nc<NCH;++nc){
        float bv = bias[nc*16+col];
        #pragma unroll
        for (int r=0;r<4;++r)
          if (lr0+r < BM) lds[(lr0+r)*LDC + nc*16+col] = acc[m][nc][r] + bv;
      }
    }
    __syncthreads();
    constexpr int WPO = WC/2;
    const size_t pbase = (size_t)p0/4;
    if (t < COUT){
      float s = 0.f, q = 0.f;
      for (int pl=0; pl<BM/4; ++pl){
        int poh = pl / WPO, pw = pl - poh*WPO;
        int r = (2*poh)*WC + 2*pw;
        float mx = fmaxf(fmaxf(lds[r*LDC+t],      lds[(r+1)*LDC+t]),
                         fmaxf(lds[(r+WC)*LDC+t], lds[(r+WC+1)*LDC+t]));
        float vv;
        if constexpr (PKOUT){
          u32 w = packsplit(mx);
          yp[(pbase + pl)*COUT + t] = w;
          vv = unpackv(w);
        } else {
          yf[(pbase + pl)*COUT + t] = mx;
          vv = mx;
        }
        s += vv; q = fmaf(vv, vv, q);
      }
      psC[(size_t)blockIdx.x*COUT + t] = s;
      qsC[(size_t)blockIdx.x*COUT + t] = q;
    }
  }
}

// ---------------- final: bnc + FC + argmax (+ aux reduce as extra block) ----------------
__global__ __launch_bounds__(256) void fc_kernel(
    const float* __restrict__ a5, const float* __restrict__ scale, const float* __restrict__ shift,
    const float* __restrict__ fcT, const float* __restrict__ fc_b,
    const float* __restrict__ auxp, float* __restrict__ outp)
{
  const int b = blockIdx.x, t = threadIdx.x;
  if (b == 256){   // aux-loss reduction block (7680 per-block partials now)
    __shared__ float s[256];
    float a=0.f;
    for (int i=t; i<7680; i+=256) a += auxp[i];
    s[t]=a; __syncthreads();
    for (int off=128; off; off>>=1){ if (t<off) s[t]+=s[t+off]; __syncthreads(); }
    if (t==0) outp[25856] = s[0] / 6220800.0f;
    return;
  }
  __shared__ float f[1024];
  __shared__ float part[256];
  __shared__ float lg[128];
  for (int e=t; e<1024; e+=256){
    int c = e & 255, hw = e >> 8;
    float v = a5[b*1024 + e];
    f[c*4 + hw] = fmaf(v, scale[c], shift[c]);
  }
  __syncthreads();
  const int o = t & 127, half = t >> 7;
  float s = 0.f;
  if (o < 100){
    const float* fp = f + half*512;
    const float* wp = fcT + half*512*100 + o;
    for (int j=0;j<512;++j) s = fmaf(fp[j], wp[j*100], s);
  }
  part[t] = s; __syncthreads();
  if (t < 128){
    float logit = part[t] + part[t+128] + ((t<100)? fc_b[t] : 0.f);
    lg[t] = (t<100)? logit : -3.0e38f;
    if (t<100) outp[b*100 + t] = logit;
  }
  __syncthreads();
  if (t==0){
    float m = lg[0]; int mi = 0;
    for (int i=1;i<100;++i){ if (lg[i] > m){ m = lg[i]; mi = i; } }
    outp[25600 + b] = (float)mi;
  }
}

// ---------------- launch ----------------
extern "C" void kernel_launch(void* const* d_in, const int* in_sizes, int n_in,
                              void* d_out, int out_size, void* d_ws, size_t ws_size,
                              hipStream_t stream)
{
  (void)in_sizes; (void)n_in; (void)out_size;
  const float* x     = (const float*)d_in[0];
  const float* enc_w = (const float*)d_in[1];
  const float* enc_b = (const float*)d_in[2];
  const float* dec_w = (const float*)d_in[3];
  const float* dec_b = (const float*)d_in[4];
  const float* red_w = (const float*)d_in[5];
  const float* red_b = (const float*)d_in[6];
  const float* bn1_g = (const float*)d_in[7];  const float* bn1_b = (const float*)d_in[8];
  const float* c1w   = (const float*)d_in[9];  const float* c1b   = (const float*)d_in[10];
  const float* bn2_g = (const float*)d_in[11]; const float* bn2_b = (const float*)d_in[12];
  const float* c2w   = (const float*)d_in[13]; const float* c2b   = (const float*)d_in[14];
  const float* bn3_g = (const float*)d_in[15]; const float* bn3_b = (const float*)d_in[16];
  const float* c3w   = (const float*)d_in[17]; const float* c3b   = (const float*)d_in[18];
  const float* bn4_g = (const float*)d_in[19]; const float* bn4_b = (const float*)d_in[20];
  const float* c4w   = (const float*)d_in[21]; const float* c4b   = (const float*)d_in[22];
  const float* bn5_g = (const float*)d_in[23]; const float* bn5_b = (const float*)d_in[24];
  const float* c5w   = (const float*)d_in[25]; const float* c5b   = (const float*)d_in[26];
  const float* bnc_g = (const float*)d_in[27]; const float* bnc_b = (const float*)d_in[28];
  const float* fc_w  = (const float*)d_in[29]; const float* fc_b  = (const float*)d_in[30];
  const int*   kp    = (const int*)d_in[31];
  float* out = (float*)d_out;
  float* ws  = (float*)d_ws;

  // ---- workspace layout (float slots) ----
  constexpr size_t OFF_ENCT = 0;
  constexpr size_t OFF_DECT = 7168;                 // decT28: 256*28 = 7168
  constexpr size_t OFF_REDT = 14336;
  constexpr size_t OFF_FCT  = 30720;
  constexpr size_t OFF_W1H = 133120, OFF_W1L = 160768;
  constexpr size_t OFF_W2H = 188416, OFF_W2L = 243712;
  constexpr size_t OFF_W3H = 299008, OFF_W3L = 391168;
  constexpr size_t OFF_W4H = 483328, OFF_W4L = 621568;
  constexpr size_t OFF_W5H = 759808, OFF_W5L = 980992;
  constexpr size_t OFF_SS1 = 1202176, OFF_SS2 = 1202304, OFF_SS3 = 1202496;
  constexpr size_t OFF_SS4 = 1202752, OFF_SS5 = 1203072, OFF_SSC = 1203456;
  constexpr size_t OFF_B    = 1303296;              // 14,745,600 (x1p | y2 | p4)
  constexpr size_t OFF_C    = 16048896;             // 9,216,000 (svv+svi | p1 | y3 | y5)
  constexpr size_t OFF_P1S  = 25264896;             // 57600 (bn1 partials, 900x64)
  constexpr size_t OFF_P1Q  = OFF_P1S + 57600;      // 57600
  constexpr size_t OFF_PCS  = OFF_P1Q + 57600;      // conv stats partials: max 1792*96
  constexpr size_t OFF_PCQ  = OFF_PCS + 172032;
  constexpr size_t OFF_AUX  = OFF_PCQ + 172032;     // 7680 aux partials
  constexpr size_t TOTALF   = OFF_AUX + 7680;       // ~103 MB
  if (ws_size < TOTALF*sizeof(float)) return;

  float* encTg = ws + OFF_ENCT;
  float* decT28 = ws + OFF_DECT; float* redT = ws + OFF_REDT; float* fcT = ws + OFF_FCT;
  u16* W1h = (u16*)(ws+OFF_W1H); u16* W1l = (u16*)(ws+OFF_W1L);
  u16* W2h = (u16*)(ws+OFF_W2H); u16* W2l = (u16*)(ws+OFF_W2L);
  u16* W3h = (u16*)(ws+OFF_W3H); u16* W3l = (u16*)(ws+OFF_W3L);
  u16* W4h = (u16*)(ws+OFF_W4H); u16* W4l = (u16*)(ws+OFF_W4L);
  u16* W5h = (u16*)(ws+OFF_W5H); u16* W5l = (u16*)(ws+OFF_W5L);
  float* ss1 = ws+OFF_SS1; float* ss2 = ws+OFF_SS2; float* ss3 = ws+OFF_SS3;
  float* ss4 = ws+OFF_SS4; float* ss5 = ws+OFF_SS5; float* ssc = ws+OFF_SSC;
  float* auxp = ws+OFF_AUX;
  float* psum1 = ws+OFF_P1S; float* psq1 = ws+OFF_P1Q;
  float* pcs = ws+OFF_PCS;  float* pcq = ws+OFF_PCQ;
  u32*   x1p = (u32*)(ws+OFF_B);
  u32*   y2p = (u32*)(ws+OFF_B);
  u32*   p4p = (u32*)(ws+OFF_B);
  float* svv = ws+OFF_C;
  unsigned char* svi = (unsigned char*)(ws+OFF_C+7372800);
  u32*   p1p = (u32*)(ws+OFF_C);
  u32*   y3p = (u32*)(ws+OFF_C);
  float* y5  = ws+OFF_C;

  prep_all<<<650, 256, 0, stream>>>(enc_w, encTg, dec_w, decT28, red_w, redT, fc_w, fcT,
                                    c1w, W1h, W1l, c2w, W2h, W2l, c3w, W3h, W3l,
                                    c4w, W4h, W4l, c5w, W5h, W5l);

  // stage A (a2 fused into a1)
  stage_a1<<<dim3(30,256), 256, 0, stream>>>(encTg, enc_b, x, kp, decT28, dec_b, svv, svi, auxp);
  stage_a3p2<<<900, 256, 0, stream>>>(svv, svi, redT, red_b, x1p, psum1, psq1);

  // bn1: finalize from a3's fused partials (64 blocks), then in-place bn+relu repack
  bn1_final<<<64, 256, 0, stream>>>(psum1, psq1, bn1_g, bn1_b, ss1, ss1+64);
  cvt_repack<64><<<14400, 256, 0, stream>>>(x1p, ss1, ss1+64, 3686400);

  // conv1 (+fused pool + bn2 stats), MW=2, BM=112 -> PACKED p1
  conv_mfma<64,96,30,30,112,2,true,true><<<1792, 256, 0, stream>>>(x1p, W1h, W1l, c1b, p1p, pcs, pcq);
  bn_finalG<96><<<96, 256, 0, stream>>>(pcs, pcq, 1792, bn2_g, bn2_b, ss2, ss2+96, 1.f/50176.f);
  cvt_repack<96><<<(1204224+255)/256, 256, 0, stream>>>(p1p, ss2, ss2+96, 1204224);

  // conv2 (+bn3 stats), MW=2, BM=128 -> PACKED y2
  conv_mfma<96,128,14,14,128,2,false,true><<<288, 256, 0, stream>>>(p1p, W2h, W2l, c2b, y2p, pcs, pcq);
  bn_finalG<128><<<128, 256, 0, stream>>>(pcs, pcq, 288, bn3_g, bn3_b, ss3, ss3+128, 1.f/36864.f);
  cvt_repack<128><<<(1179648+255)/256, 256, 0, stream>>>(y2p, ss3, ss3+128, 1179648);

  // conv3 (+bn4 stats), MW=2, BM=128 -> PACKED y3
  conv_mfma<128,160,12,12,128,2,false,true><<<200, 256, 0, stream>>>(y2p, W3h, W3l, c3b, y3p, pcs, pcq);
  bn_finalG<160><<<160, 256, 0, stream>>>(pcs, pcq, 200, bn4_g, bn4_b, ss4, ss4+160, 1.f/25600.f);
  cvt_repack<160><<<(1024000+255)/256, 256, 0, stream>>>(y3p, ss4, ss4+160, 1024000);

  // conv4 (+fused pool + bn5 stats), MW=1 -> PACKED p4
  conv_mfma<160,192,10,10,64,1,true,true><<<256, 256, 0, stream>>>(y3p, W4h, W4l, c4b, p4p, pcs, pcq);
  bn_finalG<192><<<192, 256, 0, stream>>>(pcs, pcq, 256, bn5_g, bn5_b, ss5, ss5+192, 1.f/4096.f);
  cvt_repack<192><<<(196608+255)/256, 256, 0, stream>>>(p4p, ss5, ss5+192, 196608);

  // conv5 (+bnc stats), MW=1 -> f32 y5 (fc consumes f32 directly)
  conv_mfma<192,256,4,4,64,1,false,false><<<16, 256, 0, stream>>>(p4p, W5h, W5l, c5b, y5, pcs, pcq);
  bn_finalG<256><<<256, 256, 0, stream>>>(pcs, pcq, 16, bnc_g, bnc_b, ssc, ssc+256, 1.f/1024.f);
  fc_kernel<<<257, 256, 0, stream>>>(y5, ssc, ssc+256, fcT, fc_b, auxp, out);
}

// Round 23
// 1115.644 us; speedup vs baseline: 1.1124x; 1.1124x over previous
//
#include <hip/hip_runtime.h>

#define DEV_INLINE __device__ __forceinline__
typedef unsigned long long ull;
typedef unsigned int u32;
typedef unsigned short u16;
typedef __attribute__((ext_vector_type(8))) short short8v;   // 8 bf16 (4 VGPRs)
typedef __attribute__((ext_vector_type(4))) float f32x4;

// ---------------- split-bf16 helpers ----------------
DEV_INLINE u32 rne16(float f){
  u32 u = __float_as_uint(f);
  return (u + 0x7fffu + ((u>>16)&1u)) >> 16;
}
DEV_INLINE u32 packsplit(float a){
  u32 h = rne16(a);
  float hf = __uint_as_float(h<<16);
  u32 l = rne16(a - hf);
  return h | (l<<16);
}
DEV_INLINE float unpackv(u32 w){
  return __uint_as_float(w<<16) + __uint_as_float(w & 0xffff0000u);
}

// ---------------- prep: transposes + all weight packing, one dispatch ----------------
__global__ void prep_all(const float* __restrict__ enc_w, float* __restrict__ encTg,
                         const float* __restrict__ dec_w, float* __restrict__ decT,
                         const float* __restrict__ red_w, float* __restrict__ redT,
                         const float* __restrict__ fc_w,  float* __restrict__ fcT,
                         const float* __restrict__ c1w, u16* __restrict__ W1h, u16* __restrict__ W1l,
                         const float* __restrict__ c2w, u16* __restrict__ W2h, u16* __restrict__ W2l,
                         const float* __restrict__ c3w, u16* __restrict__ W3h, u16* __restrict__ W3l,
                         const float* __restrict__ c4w, u16* __restrict__ W4h, u16* __restrict__ W4l,
                         const float* __restrict__ c5w, u16* __restrict__ W5h, u16* __restrict__ W5l)
{
  const int b = blockIdx.x, t = threadIdx.x;
  auto t2 = [&](const float* A, float* AT, int R, int C, int base){
    int i = (b-base)*256 + t; if (i < R*C){ int r=i%R, c=i/R; AT[i] = A[r*C+c]; }
  };
  auto pk = [&](const float* W, u16* wh, u16* wl, int CIN, int COUT, int base){
    int TPI = CIN/32, KS = 9*TPI;
    int tid = (b-base)*256 + t;
    if (tid >= KS*COUT) return;
    int co = tid % COUT, ks = tid / COUT;
    int tap = ks/TPI, cib = (ks - tap*TPI)*32;
    u16* dh = wh + (size_t)tid*32;
    u16* dl = wl + (size_t)tid*32;
    for (int kl=0; kl<32; ++kl){
      float w = W[((size_t)(co*CIN + cib + kl))*9 + tap];
      u32 h = rne16(w);
      float hf = __uint_as_float(h<<16);
      u32 l = rne16(w - hf);
      dh[kl] = (u16)h; dl[kl] = (u16)l;
    }
  };
  if      (b < 27)  t2(enc_w, encTg, 256, 27, 0);
  else if (b < 54)  t2(dec_w, decT, 27, 256, 27);
  else if (b < 118) t2(red_w, redT, 64, 256, 54);
  else if (b < 518) t2(fc_w,  fcT, 100, 1024, 118);
  else if (b < 525) pk(c1w, W1h, W1l, 64, 96, 518);
  else if (b < 539) pk(c2w, W2h, W2l, 96, 128, 525);
  else if (b < 562) pk(c3w, W3h, W3l, 128, 160, 539);
  else if (b < 596) pk(c4w, W4h, W4l, 160, 192, 562);
  else              pk(c5w, W5h, W5l, 192, 256, 596);
}

// ---------------- A1: enc conv + topk (DUAL chains), 256-thread blocks ----------------
// r15: 52 VGPR, occ 43%, 190us. LOCKED (r22's a2-fusion spilled: VGPR pinned
// at 64, WRITE 353MB, conflicts 2.7e7 -> reverted).
__global__ __launch_bounds__(256, 4) void stage_a1(
    const float* __restrict__ encTg, const float* __restrict__ enc_b,
    const float* __restrict__ x, const int* __restrict__ kp,
    float* __restrict__ svg_v, unsigned char* __restrict__ svg_i)
{
  __shared__ float  rows[9*32];              // 3ci x 3 rows
  __shared__ float  svf[30*33];
  __shared__ unsigned char svi[30*33];

  const int t = threadIdx.x, oh = blockIdx.x, b = blockIdx.y;
  const int k = __builtin_amdgcn_readfirstlane(*kp);
  const int wid = t>>6, lane = t&63;
  const float4* encW4 = (const float4*)encTg;

  for (int e=t; e<288; e+=256){
    int ci = e/96, r = (e/32)%3, xx = e&31;
    rows[(ci*3+r)*32+xx] = x[((b*3+ci)*32 + (oh+r))*32 + xx];
  }
  for (int e=t; e<990; e+=256){ svf[e]=0.f; svi[e]=0; }
  __syncthreads();

  const float4 eb = ((const float4*)enc_b)[lane];

  auto cnt4 = [&](unsigned c, unsigned u0, unsigned u1, unsigned u2, unsigned u3)->int{
    return __popcll(__ballot(u0>=c)) + __popcll(__ballot(u1>=c))
         + __popcll(__ballot(u2>=c)) + __popcll(__ballot(u3>=c));
  };
  auto compact = [&](float v0,float v1,float v2,float v3,
                     unsigned u0,unsigned u1,unsigned u2,unsigned u3,
                     unsigned th, int pi){
    bool k0=u0>=th, k1=u1>=th, k2=u2>=th, k3=u3>=th;
    ull B0=__ballot(k0), B1=__ballot(k1), B2=__ballot(k2), B3=__ballot(k3);
    ull below=(1ull<<lane)-1ull;
    int n0=__popcll(B0), n1=__popcll(B1), n2=__popcll(B2);
    int o0=__popcll(B0&below);
    int o1=n0+__popcll(B1&below);
    int o2=n0+n1+__popcll(B2&below);
    int o3=n0+n1+n2+__popcll(B3&below);
    float* sf = &svf[pi*33]; unsigned char* si = &svi[pi*33];
    if (k0&&o0<32){ sf[o0]=v0; si[o0]=(unsigned char)(4*lane+0); }
    if (k1&&o1<32){ sf[o1]=v1; si[o1]=(unsigned char)(4*lane+1); }
    if (k2&&o2<32){ sf[o2]=v2; si[o2]=(unsigned char)(4*lane+2); }
    if (k3&&o3<32){ sf[o3]=v3; si[o3]=(unsigned char)(4*lane+3); }
  };

  for (int it=0; it<4; ++it){
    const int pr = wid*4 + it;
    if (pr >= 15) break;                 // wave-uniform
    const int ow0 = 2*pr;

    float a0=eb.x,a1=eb.y,a2=eb.z,a3=eb.w;   // pos ow0
    float c0=eb.x,c1=eb.y,c2=eb.z,c3=eb.w;   // pos ow0+1
    #pragma unroll
    for (int ci=0; ci<3; ++ci)
      #pragma unroll
      for (int i=0;i<3;++i){
        const int rbase = (ci*3+i)*32 + ow0;
        float p0 = rows[rbase+0], p1 = rows[rbase+1];
        float p2 = rows[rbase+2], p3 = rows[rbase+3];
        float4 w0 = encW4[(ci*9+i*3+0)*64 + lane];
        float4 w1 = encW4[(ci*9+i*3+1)*64 + lane];
        float4 w2 = encW4[(ci*9+i*3+2)*64 + lane];
        a0=fmaf(w0.x,p0,a0); a1=fmaf(w0.y,p0,a1); a2=fmaf(w0.z,p0,a2); a3=fmaf(w0.w,p0,a3);
        c0=fmaf(w0.x,p1,c0); c1=fmaf(w0.y,p1,c1); c2=fmaf(w0.z,p1,c2); c3=fmaf(w0.w,p1,c3);
        a0=fmaf(w1.x,p1,a0); a1=fmaf(w1.y,p1,a1); a2=fmaf(w1.z,p1,a2); a3=fmaf(w1.w,p1,a3);
        c0=fmaf(w1.x,p2,c0); c1=fmaf(w1.y,p2,c1); c2=fmaf(w1.z,p2,c2); c3=fmaf(w1.w,p2,c3);
        a0=fmaf(w2.x,p2,a0); a1=fmaf(w2.y,p2,a1); a2=fmaf(w2.z,p2,a2); a3=fmaf(w2.w,p2,a3);
        c0=fmaf(w2.x,p3,c0); c1=fmaf(w2.y,p3,c1); c2=fmaf(w2.z,p3,c2); c3=fmaf(w2.w,p3,c3);
      }

    unsigned A0=__float_as_uint(a0)&0x7fffffffu, A1=__float_as_uint(a1)&0x7fffffffu;
    unsigned A2=__float_as_uint(a2)&0x7fffffffu, A3=__float_as_uint(a3)&0x7fffffffu;
    unsigned C0=__float_as_uint(c0)&0x7fffffffu, C1=__float_as_uint(c1)&0x7fffffffu;
    unsigned C2=__float_as_uint(c2)&0x7fffffffu, C3=__float_as_uint(c3)&0x7fffffffu;

    unsigned thA=0, thB=0;
    int dA=0, dB=0;
    for (int bit=30; bit>=0; --bit){
      if (!dA){
        unsigned c = thA | (1u<<bit);
        int n = cnt4(c,A0,A1,A2,A3);
        if (n>=k) thA=c;
        if (n==k) dA=1;
      }
      if (!dB){
        unsigned c = thB | (1u<<bit);
        int n = cnt4(c,C0,C1,C2,C3);
        if (n>=k) thB=c;
        if (n==k) dB=1;
      }
      if (dA & dB) break;
    }

    compact(a0,a1,a2,a3, A0,A1,A2,A3, thA, ow0);
    compact(c0,c1,c2,c3, C0,C1,C2,C3, thB, ow0+1);
  }
  __syncthreads();

  const size_t gbase = (size_t)b*900 + (size_t)oh*30;
  for (int e=t; e<960; e+=256){
    int jj = e/30, pi = e - jj*30;
    svg_v[(size_t)jj*230400 + gbase + pi] = svf[pi*33+jj];
    svg_i[(size_t)jj*230400 + gbase + pi] = svi[pi*33+jj];
  }
}

// ---------------- A2: dec + sigmoid + aux (float4 LDS gathers) ----------------
__global__ __launch_bounds__(256, 2) void stage_a2(
    const float* __restrict__ svg_v, const unsigned char* __restrict__ svg_i,
    const float* __restrict__ decT, const float* __restrict__ dec_b,
    const float* __restrict__ x, float* __restrict__ auxp)
{
  __shared__ __align__(16) float decl[256*28];   // 28672 B
  __shared__ float redbuf[256];
  const int t = threadIdx.x;
  for (int e=t; e<6912; e+=256){
    int r = e/27, o = e - r*27;
    decl[r*28+o] = decT[e];
  }
  __syncthreads();

  const int pos = blockIdx.x*256 + t;
  const int b = pos/900, rem = pos - b*900;
  const int oh = rem/30, ow = rem - (rem/30)*30;

  float d[27];
  #pragma unroll
  for (int o=0;o<27;++o) d[o] = dec_b[o];
  for (int jj=0; jj<32; ++jj){
    float v  = svg_v[(size_t)jj*230400 + pos];
    int  idx = (int)svg_i[(size_t)jj*230400 + pos];
    const float4* wr4 = (const float4*)(decl + idx*28);
    float4 w0=wr4[0], w1=wr4[1], w2=wr4[2], w3=wr4[3], w4=wr4[4], w5=wr4[5], w6=wr4[6];
    d[0]=fmaf(v,w0.x,d[0]);  d[1]=fmaf(v,w0.y,d[1]);  d[2]=fmaf(v,w0.z,d[2]);  d[3]=fmaf(v,w0.w,d[3]);
    d[4]=fmaf(v,w1.x,d[4]);  d[5]=fmaf(v,w1.y,d[5]);  d[6]=fmaf(v,w1.z,d[6]);  d[7]=fmaf(v,w1.w,d[7]);
    d[8]=fmaf(v,w2.x,d[8]);  d[9]=fmaf(v,w2.y,d[9]);  d[10]=fmaf(v,w2.z,d[10]); d[11]=fmaf(v,w2.w,d[11]);
    d[12]=fmaf(v,w3.x,d[12]); d[13]=fmaf(v,w3.y,d[13]); d[14]=fmaf(v,w3.z,d[14]); d[15]=fmaf(v,w3.w,d[15]);
    d[16]=fmaf(v,w4.x,d[16]); d[17]=fmaf(v,w4.y,d[17]); d[18]=fmaf(v,w4.z,d[18]); d[19]=fmaf(v,w4.w,d[19]);
    d[20]=fmaf(v,w5.x,d[20]); d[21]=fmaf(v,w5.y,d[21]); d[22]=fmaf(v,w5.z,d[22]); d[23]=fmaf(v,w5.w,d[23]);
    d[24]=fmaf(v,w6.x,d[24]); d[25]=fmaf(v,w6.y,d[25]); d[26]=fmaf(v,w6.z,d[26]);
  }
  float acc = 0.f;
  #pragma unroll
  for (int o=0;o<27;++o){
    int ci = o/9, r2 = (o - ci*9)/3, c2 = o%3;
    float tg = x[((b*3+ci)*32 + (oh+r2))*32 + (ow+c2)];
    float dv = 1.f/(1.f + __expf(-d[o]));
    float df = tg - dv;
    acc = fmaf(df, df, acc);
  }
  redbuf[t]=acc; __syncthreads();
  for (int off=128; off; off>>=1){ if (t<off) redbuf[t]+=redbuf[t+off]; __syncthreads(); }
  if (t==0) auxp[blockIdx.x] = redbuf[0];
}

// ---------------- A3: red -> packed x1p [pos][64], float4 gathers + fused bn1 stats ----------------
__global__ __launch_bounds__(256) void stage_a3p2(
    const float* __restrict__ svg_v, const unsigned char* __restrict__ svg_i,
    const float* __restrict__ redT, const float* __restrict__ red_b,
    u32* __restrict__ x1p, float* __restrict__ psum1, float* __restrict__ psq1)
{
  __shared__ __align__(16) float redl[256*68];  // 69632 B, row = 17 float4
  __shared__ u32   obuf[256*65];                // 66560 B
  const int t = threadIdx.x;
  for (int e=t; e<16384; e+=256) redl[(e>>6)*68 + (e&63)] = redT[e];
  __syncthreads();

  const int pos = blockIdx.x*256 + t;

  float v[32]; int a[32];
  #pragma unroll
  for (int j=0;j<32;++j) v[j] = svg_v[(size_t)j*230400 + pos];
  #pragma unroll
  for (int j=0;j<32;++j) a[j] = (int)svg_i[(size_t)j*230400 + pos]*17; // float4-row

  const float4* redl4 = (const float4*)redl;
  #pragma unroll 2
  for (int ocb=0; ocb<16; ++ocb){
    float s0 = red_b[4*ocb+0], s1 = red_b[4*ocb+1];
    float s2 = red_b[4*ocb+2], s3 = red_b[4*ocb+3];
    #pragma unroll
    for (int j=0;j<32;++j){
      float4 w = redl4[a[j] + ocb];
      s0 = fmaf(v[j], w.x, s0); s1 = fmaf(v[j], w.y, s1);
      s2 = fmaf(v[j], w.z, s2); s3 = fmaf(v[j], w.w, s3);
    }
    obuf[t*65 + 4*ocb+0] = packsplit(s0);
    obuf[t*65 + 4*ocb+1] = packsplit(s1);
    obuf[t*65 + 4*ocb+2] = packsplit(s2);
    obuf[t*65 + 4*ocb+3] = packsplit(s3);
  }
  __syncthreads();   // all redl reads + obuf writes complete

  const size_t base = (size_t)blockIdx.x*16384;
  float s = 0.f, q = 0.f;
  for (int e=t; e<16384; e+=256){
    u32 w = obuf[(e>>6)*65 + (e&63)];
    x1p[base + e] = w;
    float vv = unpackv(w);
    s += vv; q = fmaf(vv, vv, q);
  }
  float* ls = redl; float* lq = redl + 256;
  ls[t] = s; lq[t] = q; __syncthreads();
  if (t < 128){ ls[t] += ls[t+128]; lq[t] += lq[t+128]; } __syncthreads();
  if (t < 64){
    psum1[(size_t)blockIdx.x*64 + t] = ls[t] + ls[t+64];
    psq1 [(size_t)blockIdx.x*64 + t] = lq[t] + lq[t+64];
  }
}

// ---------------- bn1 finalize: one block per channel (64 blocks) ----------------
__global__ __launch_bounds__(256) void bn1_final(
    const float* __restrict__ ps, const float* __restrict__ pq,
    const float* __restrict__ g, const float* __restrict__ b2,
    float* __restrict__ sc, float* __restrict__ sh)
{
  __shared__ float ls[256], lq[256];
  const int c = blockIdx.x, t = threadIdx.x;
  float s=0.f, q=0.f;
  for (int i=t; i<900; i+=256){ s += ps[(size_t)i*64+c]; q += pq[(size_t)i*64+c]; }
  ls[t]=s; lq[t]=q; __syncthreads();
  for (int off=128; off; off>>=1){
    if (t<off){ ls[t]+=ls[t+off]; lq[t]+=lq[t+off]; } __syncthreads();
  }
  if (t==0){
    constexpr float inv_n = 1.f/230400.f;
    float m = ls[0]*inv_n;
    float var = fmaf(lq[0], inv_n, -m*m);
    float rs = rsqrtf(var + 1e-5f);
    float scale = g[c]*rs;
    sc[c] = scale;
    sh[c] = fmaf(-m, scale, b2[c]);
  }
}

// ---------------- generic BN finalize: ONE BLOCK PER CHANNEL ----------------
template<int C>
__global__ __launch_bounds__(256) void bn_finalG(
    const float* __restrict__ ps, const float* __restrict__ pq, int G,
    const float* __restrict__ g, const float* __restrict__ b2,
    float* __restrict__ sc, float* __restrict__ sh, float inv_n)
{
  __shared__ float ls[256], lq[256];
  const int c = blockIdx.x, t = threadIdx.x;
  float s=0.f, q=0.f;
  for (int i=t; i<G; i+=256){ s += ps[(size_t)i*C+c]; q += pq[(size_t)i*C+c]; }
  ls[t]=s; lq[t]=q; __syncthreads();
  for (int off=128; off; off>>=1){
    if (t<off){ ls[t]+=ls[t+off]; lq[t]+=lq[t+off]; } __syncthreads();
  }
  if (t==0){
    float m = ls[0]*inv_n;
    float var = fmaf(lq[0], inv_n, -m*m);
    float rs = rsqrtf(var + 1e-5f);
    float scale = g[c]*rs;
    sc[c] = scale;
    sh[c] = fmaf(-m, scale, b2[c]);
  }
}

// ---------------- cvt: in-place packed->packed BN+ReLU ----------------
template<int C>
__global__ void cvt_repack(u32* __restrict__ xp, const float* __restrict__ sc,
                           const float* __restrict__ sh, int total4){
  int i = blockIdx.x*256 + threadIdx.x;
  if (i >= total4) return;
  uint4* p = (uint4*)xp;
  uint4 w = p[i];
  int cb = (i*4) % C;     // C%4==0
  w.x = packsplit(fmaxf(fmaf(unpackv(w.x), sc[cb+0], sh[cb+0]), 0.f));
  w.y = packsplit(fmaxf(fmaf(unpackv(w.y), sc[cb+1], sh[cb+1]), 0.f));
  w.z = packsplit(fmaxf(fmaf(unpackv(w.z), sc[cb+2], sh[cb+2]), 0.f));
  w.w = packsplit(fmaxf(fmaf(unpackv(w.w), sc[cb+3], sh[cb+3]), 0.f));
  p[i] = w;
}

// ---------------- conv via MFMA implicit GEMM, 3x bf16 split + fused BN partial stats ----------------
template<int CIN,int COUT,int HIN,int WIN,int BM,int MW,bool POOL,bool PKOUT>
__global__ __launch_bounds__(256) void conv_mfma(
    const u32* __restrict__ xp, const u16* __restrict__ wh,
    const u16* __restrict__ wl, const float* __restrict__ bias,
    void* __restrict__ y_, float* __restrict__ psC, float* __restrict__ qsC)
{
  constexpr int HC=HIN-2, WC=WIN-2, TPI=CIN/32, KS=9*TPI, NCH=COUT/16;
  const int t = threadIdx.x, wid = t>>6, lane = t&63;
  const int p0 = blockIdx.x*BM;
  const int colg = lane>>4;
  const int col = lane&15;
  float* yf = (float*)y_;
  u32*   yp = (u32*)y_;

  const u32* Aptr[MW];
  #pragma unroll
  for (int m=0;m<MW;++m){
    int l = (wid*MW+m)*16 + col;
    int lc = l < BM ? l : BM-1;
    int p = p0 + lc;
    int b = p/(HC*WC); int rem = p - b*(HC*WC);
    int oh = rem/WC, ow = rem - (rem/WC)*WC;
    Aptr[m] = xp + ((size_t)((b*HIN+oh)*WIN+ow))*CIN + colg*8;
  }
  const size_t wb = (size_t)col*32 + colg*8;

  f32x4 acc[MW][NCH];
  #pragma unroll
  for (int m=0;m<MW;++m)
    #pragma unroll
    for (int nc=0;nc<NCH;++nc) acc[m][nc] = (f32x4){0.f,0.f,0.f,0.f};

  for (int ks=0; ks<KS; ++ks){
    const int tap = ks/TPI, cib = (ks - tap*TPI)*32;
    const int kh = tap/3, kw = tap - kh*3;
    short8v ah[MW], al[MW];
    #pragma unroll
    for (int m=0;m<MW;++m){
      const u32* ap = Aptr[m] + (kh*WIN + kw)*CIN + cib;
      uint4 qa = *(const uint4*)(ap);
      uint4 qb = *(const uint4*)(ap+4);
      ah[m][0]=(short)(qa.x&0xffffu); al[m][0]=(short)(qa.x>>16);
      ah[m][1]=(short)(qa.y&0xffffu); al[m][1]=(short)(qa.y>>16);
      ah[m][2]=(short)(qa.z&0xffffu); al[m][2]=(short)(qa.z>>16);
      ah[m][3]=(short)(qa.w&0xffffu); al[m][3]=(short)(qa.w>>16);
      ah[m][4]=(short)(qb.x&0xffffu); al[m][4]=(short)(qb.x>>16);
      ah[m][5]=(short)(qb.y&0xffffu); al[m][5]=(short)(qb.y>>16);
      ah[m][6]=(short)(qb.z&0xffffu); al[m][6]=(short)(qb.z>>16);
      ah[m][7]=(short)(qb.w&0xffffu); al[m][7]=(short)(qb.w>>16);
    }
    const u16* whp = wh + (size_t)ks*COUT*32 + wb;
    const u16* wlp = wl + (size_t)ks*COUT*32 + wb;
    #pragma unroll
    for (int nc=0;nc<NCH;++nc){
      short8v bh = *(const short8v*)(whp + nc*512);
      short8v bl = *(const short8v*)(wlp + nc*512);
      #pragma unroll
      for (int m=0;m<MW;++m){
        acc[m][nc] = __builtin_amdgcn_mfma_f32_16x16x32_bf16(ah[m], bh, acc[m][nc], 0,0,0);
        acc[m][nc] = __builtin_amdgcn_mfma_f32_16x16x32_bf16(ah[m], bl, acc[m][nc], 0,0,0);
        acc[m][nc] = __builtin_amdgcn_mfma_f32_16x16x32_bf16(al[m], bh, acc[m][nc], 0,0,0);
      }
    }
  }

  if constexpr (!POOL){
    __shared__ float ldsS[4][COUT], ldsQ[4][COUT];
    float sacc[NCH], qacc[NCH];
    #pragma unroll
    for (int nc=0;nc<NCH;++nc){ sacc[nc]=0.f; qacc[nc]=0.f; }
    #pragma unroll
    for (int m=0;m<MW;++m){
      const int lr0 = (wid*MW+m)*16 + colg*4;
      #pragma unroll
      for (int nc=0;nc<NCH;++nc){
        float bv = bias[nc*16+col];
        #pragma unroll
        for (int r=0;r<4;++r)
          if (lr0+r < BM){
            float ov = acc[m][nc][r] + bv;
            float vv;
            if constexpr (PKOUT){
              u32 w = packsplit(ov);
              yp[(size_t)(p0+lr0+r)*COUT + nc*16+col] = w;
              vv = unpackv(w);
            } else {
              yf[(size_t)(p0+lr0+r)*COUT + nc*16+col] = ov;
              vv = ov;
            }
            sacc[nc] += vv; qacc[nc] = fmaf(vv, vv, qacc[nc]);
          }
      }
    }
    #pragma unroll
    for (int nc=0;nc<NCH;++nc){
      float s_ = sacc[nc], q_ = qacc[nc];
      s_ += __shfl_xor(s_, 16); q_ += __shfl_xor(q_, 16);
      s_ += __shfl_xor(s_, 32); q_ += __shfl_xor(q_, 32);
      if (colg == 0){ ldsS[wid][nc*16+col] = s_; ldsQ[wid][nc*16+col] = q_; }
    }
    __syncthreads();
    if (t < COUT){
      psC[(size_t)blockIdx.x*COUT + t] = ldsS[0][t]+ldsS[1][t]+ldsS[2][t]+ldsS[3][t];
      qsC[(size_t)blockIdx.x*COUT + t] = ldsQ[0][t]+ldsQ[1][t]+ldsQ[2][t]+ldsQ[3][t];
    }
  } else {
    constexpr int LDC = COUT+4;
    __shared__ float lds[BM*LDC];
    #pragma unroll
    for (int m=0;m<MW;++m){
      const int lr0 = (wid*MW+m)*16 + colg*4;
      #pragma unroll
      for (int nc=0;nc<NCH;++nc){
        float bv = bias[nc*16+col];
        #pragma unroll
        for (int r=0;r<4;++r)
          if (lr0+r < BM) lds[(lr0+r)*LDC + nc*16+col] = acc[m][nc][r] + bv;
      }
    }
    __syncthreads();
    constexpr int WPO = WC/2;
    const size_t pbase = (size_t)p0/4;
    if (t < COUT){
      float s = 0.f, q = 0.f;
      for (int pl=0; pl<BM/4; ++pl){
        int poh = pl / WPO, pw = pl - poh*WPO;
        int r = (2*poh)*WC + 2*pw;
        float mx = fmaxf(fmaxf(lds[r*LDC+t],      lds[(r+1)*LDC+t]),
                         fmaxf(lds[(r+WC)*LDC+t], lds[(r+WC+1)*LDC+t]));
        float vv;
        if constexpr (PKOUT){
          u32 w = packsplit(mx);
          yp[(pbase + pl)*COUT + t] = w;
          vv = unpackv(w);
        } else {
          yf[(pbase + pl)*COUT + t] = mx;
          vv = mx;
        }
        s += vv; q = fmaf(vv, vv, q);
      }
      psC[(size_t)blockIdx.x*COUT + t] = s;
      qsC[(size_t)blockIdx.x*COUT + t] = q;
    }
  }
}

// ---------------- final: bnc + FC + argmax (+ aux reduce as extra block) ----------------
__global__ __launch_bounds__(256) void fc_kernel(
    const float* __restrict__ a5, const float* __restrict__ scale, const float* __restrict__ shift,
    const float* __restrict__ fcT, const float* __restrict__ fc_b,
    const float* __restrict__ auxp, float* __restrict__ outp)
{
  const int b = blockIdx.x, t = threadIdx.x;
  if (b == 256){   // aux-loss reduction block
    __shared__ float s[256];
    float a=0.f;
    for (int i=t; i<900; i+=256) a += auxp[i];
    s[t]=a; __syncthreads();
    for (int off=128; off; off>>=1){ if (t<off) s[t]+=s[t+off]; __syncthreads(); }
    if (t==0) outp[25856] = s[0] / 6220800.0f;
    return;
  }
  __shared__ float f[1024];
  __shared__ float part[256];
  __shared__ float lg[128];
  for (int e=t; e<1024; e+=256){
    int c = e & 255, hw = e >> 8;
    float v = a5[b*1024 + e];
    f[c*4 + hw] = fmaf(v, scale[c], shift[c]);
  }
  __syncthreads();
  const int o = t & 127, half = t >> 7;
  float s = 0.f;
  if (o < 100){
    const float* fp = f + half*512;
    const float* wp = fcT + half*512*100 + o;
    for (int j=0;j<512;++j) s = fmaf(fp[j], wp[j*100], s);
  }
  part[t] = s; __syncthreads();
  if (t < 128){
    float logit = part[t] + part[t+128] + ((t<100)? fc_b[t] : 0.f);
    lg[t] = (t<100)? logit : -3.0e38f;
    if (t<100) outp[b*100 + t] = logit;
  }
  __syncthreads();
  if (t==0){
    float m = lg[0]; int mi = 0;
    for (int i=1;i<100;++i){ if (lg[i] > m){ m = lg[i]; mi = i; } }
    outp[25600 + b] = (float)mi;
  }
}

// ---------------- launch ----------------
extern "C" void kernel_launch(void* const* d_in, const int* in_sizes, int n_in,
                              void* d_out, int out_size, void* d_ws, size_t ws_size,
                              hipStream_t stream)
{
  (void)in_sizes; (void)n_in; (void)out_size;
  const float* x     = (const float*)d_in[0];
  const float* enc_w = (const float*)d_in[1];
  const float* enc_b = (const float*)d_in[2];
  const float* dec_w = (const float*)d_in[3];
  const float* dec_b = (const float*)d_in[4];
  const float* red_w = (const float*)d_in[5];
  const float* red_b = (const float*)d_in[6];
  const float* bn1_g = (const float*)d_in[7];  const float* bn1_b = (const float*)d_in[8];
  const float* c1w   = (const float*)d_in[9];  const float* c1b   = (const float*)d_in[10];
  const float* bn2_g = (const float*)d_in[11]; const float* bn2_b = (const float*)d_in[12];
  const float* c2w   = (const float*)d_in[13]; const float* c2b   = (const float*)d_in[14];
  const float* bn3_g = (const float*)d_in[15]; const float* bn3_b = (const float*)d_in[16];
  const float* c3w   = (const float*)d_in[17]; const float* c3b   = (const float*)d_in[18];
  const float* bn4_g = (const float*)d_in[19]; const float* bn4_b = (const float*)d_in[20];
  const float* c4w   = (const float*)d_in[21]; const float* c4b   = (const float*)d_in[22];
  const float* bn5_g = (const float*)d_in[23]; const float* bn5_b = (const float*)d_in[24];
  const float* c5w   = (const float*)d_in[25]; const float* c5b   = (const float*)d_in[26];
  const float* bnc_g = (const float*)d_in[27]; const float* bnc_b = (const float*)d_in[28];
  const float* fc_w  = (const float*)d_in[29]; const float* fc_b  = (const float*)d_in[30];
  const int*   kp    = (const int*)d_in[31];
  float* out = (float*)d_out;
  float* ws  = (float*)d_ws;

  // ---- workspace layout (float slots) ----
  constexpr size_t OFF_ENCT = 0;
  constexpr size_t OFF_DECT = 7168;
  constexpr size_t OFF_REDT = 14336;
  constexpr size_t OFF_FCT  = 30720;
  constexpr size_t OFF_W1H = 133120, OFF_W1L = 160768;
  constexpr size_t OFF_W2H = 188416, OFF_W2L = 243712;
  constexpr size_t OFF_W3H = 299008, OFF_W3L = 391168;
  constexpr size_t OFF_W4H = 483328, OFF_W4L = 621568;
  constexpr size_t OFF_W5H = 759808, OFF_W5L = 980992;
  constexpr size_t OFF_SS1 = 1202176, OFF_SS2 = 1202304, OFF_SS3 = 1202496;
  constexpr size_t OFF_SS4 = 1202752, OFF_SS5 = 1203072, OFF_SSC = 1203456;
  constexpr size_t OFF_AUX  = 1302272;              // 900 aux
  constexpr size_t OFF_B    = 1303296;              // 14,745,600 (x1p | y2 | p4)
  constexpr size_t OFF_C    = 16048896;             // 9,216,000 (svv+svi | p1 | y3 | y5)
  constexpr size_t OFF_P1S  = 25264896;             // 57600 (bn1 partials, 900x64)
  constexpr size_t OFF_P1Q  = OFF_P1S + 57600;      // 57600
  constexpr size_t OFF_PCS  = OFF_P1Q + 57600;      // conv stats partials: max 1792*96
  constexpr size_t OFF_PCQ  = OFF_PCS + 172032;
  constexpr size_t TOTALF   = OFF_PCQ + 172032;     // ~103 MB
  if (ws_size < TOTALF*sizeof(float)) return;

  float* encTg = ws + OFF_ENCT;
  float* decT = ws + OFF_DECT; float* redT = ws + OFF_REDT; float* fcT = ws + OFF_FCT;
  u16* W1h = (u16*)(ws+OFF_W1H); u16* W1l = (u16*)(ws+OFF_W1L);
  u16* W2h = (u16*)(ws+OFF_W2H); u16* W2l = (u16*)(ws+OFF_W2L);
  u16* W3h = (u16*)(ws+OFF_W3H); u16* W3l = (u16*)(ws+OFF_W3L);
  u16* W4h = (u16*)(ws+OFF_W4H); u16* W4l = (u16*)(ws+OFF_W4L);
  u16* W5h = (u16*)(ws+OFF_W5H); u16* W5l = (u16*)(ws+OFF_W5L);
  float* ss1 = ws+OFF_SS1; float* ss2 = ws+OFF_SS2; float* ss3 = ws+OFF_SS3;
  float* ss4 = ws+OFF_SS4; float* ss5 = ws+OFF_SS5; float* ssc = ws+OFF_SSC;
  float* auxp = ws+OFF_AUX;
  float* psum1 = ws+OFF_P1S; float* psq1 = ws+OFF_P1Q;
  float* pcs = ws+OFF_PCS;  float* pcq = ws+OFF_PCQ;
  u32*   x1p = (u32*)(ws+OFF_B);
  u32*   y2p = (u32*)(ws+OFF_B);
  u32*   p4p = (u32*)(ws+OFF_B);
  float* svv = ws+OFF_C;
  unsigned char* svi = (unsigned char*)(ws+OFF_C+7372800);
  u32*   p1p = (u32*)(ws+OFF_C);
  u32*   y3p = (u32*)(ws+OFF_C);
  float* y5  = ws+OFF_C;

  prep_all<<<650, 256, 0, stream>>>(enc_w, encTg, dec_w, decT, red_w, redT, fc_w, fcT,
                                    c1w, W1h, W1l, c2w, W2h, W2l, c3w, W3h, W3l,
                                    c4w, W4h, W4l, c5w, W5h, W5l);

  // stage A
  stage_a1<<<dim3(30,256), 256, 0, stream>>>(encTg, enc_b, x, kp, svv, svi);
  stage_a2<<<900, 256, 0, stream>>>(svv, svi, decT, dec_b, x, auxp);
  stage_a3p2<<<900, 256, 0, stream>>>(svv, svi, redT, red_b, x1p, psum1, psq1);

  // bn1: finalize from a3's fused partials (64 blocks), then in-place bn+relu repack
  bn1_final<<<64, 256, 0, stream>>>(psum1, psq1, bn1_g, bn1_b, ss1, ss1+64);
  cvt_repack<64><<<14400, 256, 0, stream>>>(x1p, ss1, ss1+64, 3686400);

  // conv1 (+fused pool + bn2 stats), MW=2, BM=112 -> PACKED p1
  conv_mfma<64,96,30,30,112,2,true,true><<<1792, 256, 0, stream>>>(x1p, W1h, W1l, c1b, p1p, pcs, pcq);
  bn_finalG<96><<<96, 256, 0, stream>>>(pcs, pcq, 1792, bn2_g, bn2_b, ss2, ss2+96, 1.f/50176.f);
  cvt_repack<96><<<(1204224+255)/256, 256, 0, stream>>>(p1p, ss2, ss2+96, 1204224);

  // conv2 (+bn3 stats), MW=2, BM=128 -> PACKED y2
  conv_mfma<96,128,14,14,128,2,false,true><<<288, 256, 0, stream>>>(p1p, W2h, W2l, c2b, y2p, pcs, pcq);
  bn_finalG<128><<<128, 256, 0, stream>>>(pcs, pcq, 288, bn3_g, bn3_b, ss3, ss3+128, 1.f/36864.f);
  cvt_repack<128><<<(1179648+255)/256, 256, 0, stream>>>(y2p, ss3, ss3+128, 1179648);

  // conv3 (+bn4 stats), MW=2, BM=128 -> PACKED y3
  conv_mfma<128,160,12,12,128,2,false,true><<<200, 256, 0, stream>>>(y2p, W3h, W3l, c3b, y3p, pcs, pcq);
  bn_finalG<160><<<160, 256, 0, stream>>>(pcs, pcq, 200, bn4_g, bn4_b, ss4, ss4+160, 1.f/25600.f);
  cvt_repack<160><<<(1024000+255)/256, 256, 0, stream>>>(y3p, ss4, ss4+160, 1024000);

  // conv4 (+fused pool + bn5 stats), MW=1 -> PACKED p4
  conv_mfma<160,192,10,10,64,1,true,true><<<256, 256, 0, stream>>>(y3p, W4h, W4l, c4b, p4p, pcs, pcq);
  bn_finalG<192><<<192, 256, 0, stream>>>(pcs, pcq, 256, bn5_g, bn5_b, ss5, ss5+192, 1.f/4096.f);
  cvt_repack<192><<<(196608+255)/256, 256, 0, stream>>>(p4p, ss5, ss5+192, 196608);

  // conv5 (+bnc stats), MW=1 -> f32 y5 (fc consumes f32 directly)
  conv_mfma<192,256,4,4,64,1,false,false><<<16, 256, 0, stream>>>(p4p, W5h, W5l, c5b, y5, pcs, pcq);
  bn_finalG<256><<<256, 256, 0, stream>>>(pcs, pcq, 16, bnc_g, bnc_b, ssc, ssc+256, 1.f/1024.f);
  fc_kernel<<<257, 256, 0, stream>>>(y5, ssc, ssc+256, fcT, fc_b, auxp, out);
}

// Round 24
// 1095.854 us; speedup vs baseline: 1.1325x; 1.0181x over previous
//
#include <hip/hip_runtime.h>

#define DEV_INLINE __device__ __forceinline__
typedef unsigned long long ull;
typedef unsigned int u32;
typedef unsigned short u16;
typedef __attribute__((ext_vector_type(8))) short short8v;   // 8 bf16 (4 VGPRs)
typedef __attribute__((ext_vector_type(4))) float f32x4;

// ---------------- split-bf16 helpers ----------------
DEV_INLINE u32 rne16(float f){
  u32 u = __float_as_uint(f);
  return (u + 0x7fffu + ((u>>16)&1u)) >> 16;
}
DEV_INLINE u32 packsplit(float a){
  u32 h = rne16(a);
  float hf = __uint_as_float(h<<16);
  u32 l = rne16(a - hf);
  return h | (l<<16);
}
DEV_INLINE float unpackv(u32 w){
  return __uint_as_float(w<<16) + __uint_as_float(w & 0xffff0000u);
}

// ---------------- prep: transposes + ELEMENT-PARALLEL weight packing ----------------
// r23->r24: pk was 32 serial stride-36B reads/thread (latency chain); now one
// element per thread (1 read + 2 coalesced u16 writes). Identical output bytes.
// block ranges: t2: enc 0-26, dec 27-53, red 54-117, fc 118-517;
// pk: c1 518-733, c2 734-1165, c3 1166-1885, c4 1886-2965, c5 2966-4693.
__global__ void prep_all(const float* __restrict__ enc_w, float* __restrict__ encTg,
                         const float* __restrict__ dec_w, float* __restrict__ decT,
                         const float* __restrict__ red_w, float* __restrict__ redT,
                         const float* __restrict__ fc_w,  float* __restrict__ fcT,
                         const float* __restrict__ c1w, u16* __restrict__ W1h, u16* __restrict__ W1l,
                         const float* __restrict__ c2w, u16* __restrict__ W2h, u16* __restrict__ W2l,
                         const float* __restrict__ c3w, u16* __restrict__ W3h, u16* __restrict__ W3l,
                         const float* __restrict__ c4w, u16* __restrict__ W4h, u16* __restrict__ W4l,
                         const float* __restrict__ c5w, u16* __restrict__ W5h, u16* __restrict__ W5l)
{
  const int b = blockIdx.x, t = threadIdx.x;
  auto t2 = [&](const float* A, float* AT, int R, int C, int base){
    int i = (b-base)*256 + t; if (i < R*C){ int r=i%R, c=i/R; AT[i] = A[r*C+c]; }
  };
  auto pk = [&](const float* W, u16* wh, u16* wl, int CIN, int COUT, int base){
    int TPI = CIN/32;
    int eid = (b-base)*256 + t;
    if (eid >= 9*TPI*COUT*32) return;
    int kl = eid & 31;
    int rem = eid >> 5;            // ks*COUT + co (matches output layout)
    int co = rem % COUT, ks = rem / COUT;
    int tap = ks/TPI, cib = (ks - tap*TPI)*32;
    float w = W[((size_t)(co*CIN + cib + kl))*9 + tap];
    u32 h = rne16(w);
    float hf = __uint_as_float(h<<16);
    u32 l = rne16(w - hf);
    wh[(size_t)rem*32 + kl] = (u16)h;
    wl[(size_t)rem*32 + kl] = (u16)l;
  };
  if      (b < 27)   t2(enc_w, encTg, 256, 27, 0);
  else if (b < 54)   t2(dec_w, decT, 27, 256, 27);
  else if (b < 118)  t2(red_w, redT, 64, 256, 54);
  else if (b < 518)  t2(fc_w,  fcT, 100, 1024, 118);
  else if (b < 734)  pk(c1w, W1h, W1l, 64, 96, 518);
  else if (b < 1166) pk(c2w, W2h, W2l, 96, 128, 734);
  else if (b < 1886) pk(c3w, W3h, W3l, 128, 160, 1166);
  else if (b < 2966) pk(c4w, W4h, W4l, 160, 192, 1886);
  else               pk(c5w, W5h, W5l, 192, 256, 2966);
}

// ---------------- A1: enc conv + topk (DUAL chains), 256-thread blocks ----------------
// r15: 52 VGPR, occ 43%, 190us. LOCKED.
__global__ __launch_bounds__(256, 4) void stage_a1(
    const float* __restrict__ encTg, const float* __restrict__ enc_b,
    const float* __restrict__ x, const int* __restrict__ kp,
    float* __restrict__ svg_v, unsigned char* __restrict__ svg_i)
{
  __shared__ float  rows[9*32];              // 3ci x 3 rows
  __shared__ float  svf[30*33];
  __shared__ unsigned char svi[30*33];

  const int t = threadIdx.x, oh = blockIdx.x, b = blockIdx.y;
  const int k = __builtin_amdgcn_readfirstlane(*kp);
  const int wid = t>>6, lane = t&63;
  const float4* encW4 = (const float4*)encTg;

  for (int e=t; e<288; e+=256){
    int ci = e/96, r = (e/32)%3, xx = e&31;
    rows[(ci*3+r)*32+xx] = x[((b*3+ci)*32 + (oh+r))*32 + xx];
  }
  for (int e=t; e<990; e+=256){ svf[e]=0.f; svi[e]=0; }
  __syncthreads();

  const float4 eb = ((const float4*)enc_b)[lane];

  auto cnt4 = [&](unsigned c, unsigned u0, unsigned u1, unsigned u2, unsigned u3)->int{
    return __popcll(__ballot(u0>=c)) + __popcll(__ballot(u1>=c))
         + __popcll(__ballot(u2>=c)) + __popcll(__ballot(u3>=c));
  };
  auto compact = [&](float v0,float v1,float v2,float v3,
                     unsigned u0,unsigned u1,unsigned u2,unsigned u3,
                     unsigned th, int pi){
    bool k0=u0>=th, k1=u1>=th, k2=u2>=th, k3=u3>=th;
    ull B0=__ballot(k0), B1=__ballot(k1), B2=__ballot(k2), B3=__ballot(k3);
    ull below=(1ull<<lane)-1ull;
    int n0=__popcll(B0), n1=__popcll(B1), n2=__popcll(B2);
    int o0=__popcll(B0&below);
    int o1=n0+__popcll(B1&below);
    int o2=n0+n1+__popcll(B2&below);
    int o3=n0+n1+n2+__popcll(B3&below);
    float* sf = &svf[pi*33]; unsigned char* si = &svi[pi*33];
    if (k0&&o0<32){ sf[o0]=v0; si[o0]=(unsigned char)(4*lane+0); }
    if (k1&&o1<32){ sf[o1]=v1; si[o1]=(unsigned char)(4*lane+1); }
    if (k2&&o2<32){ sf[o2]=v2; si[o2]=(unsigned char)(4*lane+2); }
    if (k3&&o3<32){ sf[o3]=v3; si[o3]=(unsigned char)(4*lane+3); }
  };

  for (int it=0; it<4; ++it){
    const int pr = wid*4 + it;
    if (pr >= 15) break;                 // wave-uniform
    const int ow0 = 2*pr;

    float a0=eb.x,a1=eb.y,a2=eb.z,a3=eb.w;   // pos ow0
    float c0=eb.x,c1=eb.y,c2=eb.z,c3=eb.w;   // pos ow0+1
    #pragma unroll
    for (int ci=0; ci<3; ++ci)
      #pragma unroll
      for (int i=0;i<3;++i){
        const int rbase = (ci*3+i)*32 + ow0;
        float p0 = rows[rbase+0], p1 = rows[rbase+1];
        float p2 = rows[rbase+2], p3 = rows[rbase+3];
        float4 w0 = encW4[(ci*9+i*3+0)*64 + lane];
        float4 w1 = encW4[(ci*9+i*3+1)*64 + lane];
        float4 w2 = encW4[(ci*9+i*3+2)*64 + lane];
        a0=fmaf(w0.x,p0,a0); a1=fmaf(w0.y,p0,a1); a2=fmaf(w0.z,p0,a2); a3=fmaf(w0.w,p0,a3);
        c0=fmaf(w0.x,p1,c0); c1=fmaf(w0.y,p1,c1); c2=fmaf(w0.z,p1,c2); c3=fmaf(w0.w,p1,c3);
        a0=fmaf(w1.x,p1,a0); a1=fmaf(w1.y,p1,a1); a2=fmaf(w1.z,p1,a2); a3=fmaf(w1.w,p1,a3);
        c0=fmaf(w1.x,p2,c0); c1=fmaf(w1.y,p2,c1); c2=fmaf(w1.z,p2,c2); c3=fmaf(w1.w,p2,c3);
        a0=fmaf(w2.x,p2,a0); a1=fmaf(w2.y,p2,a1); a2=fmaf(w2.z,p2,a2); a3=fmaf(w2.w,p2,a3);
        c0=fmaf(w2.x,p3,c0); c1=fmaf(w2.y,p3,c1); c2=fmaf(w2.z,p3,c2); c3=fmaf(w2.w,p3,c3);
      }

    unsigned A0=__float_as_uint(a0)&0x7fffffffu, A1=__float_as_uint(a1)&0x7fffffffu;
    unsigned A2=__float_as_uint(a2)&0x7fffffffu, A3=__float_as_uint(a3)&0x7fffffffu;
    unsigned C0=__float_as_uint(c0)&0x7fffffffu, C1=__float_as_uint(c1)&0x7fffffffu;
    unsigned C2=__float_as_uint(c2)&0x7fffffffu, C3=__float_as_uint(c3)&0x7fffffffu;

    unsigned thA=0, thB=0;
    int dA=0, dB=0;
    for (int bit=30; bit>=0; --bit){
      if (!dA){
        unsigned c = thA | (1u<<bit);
        int n = cnt4(c,A0,A1,A2,A3);
        if (n>=k) thA=c;
        if (n==k) dA=1;
      }
      if (!dB){
        unsigned c = thB | (1u<<bit);
        int n = cnt4(c,C0,C1,C2,C3);
        if (n>=k) thB=c;
        if (n==k) dB=1;
      }
      if (dA & dB) break;
    }

    compact(a0,a1,a2,a3, A0,A1,A2,A3, thA, ow0);
    compact(c0,c1,c2,c3, C0,C1,C2,C3, thB, ow0+1);
  }
  __syncthreads();

  const size_t gbase = (size_t)b*900 + (size_t)oh*30;
  for (int e=t; e<960; e+=256){
    int jj = e/30, pi = e - jj*30;
    svg_v[(size_t)jj*230400 + gbase + pi] = svf[pi*33+jj];
    svg_i[(size_t)jj*230400 + gbase + pi] = svi[pi*33+jj];
  }
}

// ---------------- A2: dec + sigmoid + aux (float4 LDS gathers) ----------------
__global__ __launch_bounds__(256, 2) void stage_a2(
    const float* __restrict__ svg_v, const unsigned char* __restrict__ svg_i,
    const float* __restrict__ decT, const float* __restrict__ dec_b,
    const float* __restrict__ x, float* __restrict__ auxp)
{
  __shared__ __align__(16) float decl[256*28];   // 28672 B
  __shared__ float redbuf[256];
  const int t = threadIdx.x;
  for (int e=t; e<6912; e+=256){
    int r = e/27, o = e - r*27;
    decl[r*28+o] = decT[e];
  }
  __syncthreads();

  const int pos = blockIdx.x*256 + t;
  const int b = pos/900, rem = pos - b*900;
  const int oh = rem/30, ow = rem - (rem/30)*30;

  float d[27];
  #pragma unroll
  for (int o=0;o<27;++o) d[o] = dec_b[o];
  for (int jj=0; jj<32; ++jj){
    float v  = svg_v[(size_t)jj*230400 + pos];
    int  idx = (int)svg_i[(size_t)jj*230400 + pos];
    const float4* wr4 = (const float4*)(decl + idx*28);
    float4 w0=wr4[0], w1=wr4[1], w2=wr4[2], w3=wr4[3], w4=wr4[4], w5=wr4[5], w6=wr4[6];
    d[0]=fmaf(v,w0.x,d[0]);  d[1]=fmaf(v,w0.y,d[1]);  d[2]=fmaf(v,w0.z,d[2]);  d[3]=fmaf(v,w0.w,d[3]);
    d[4]=fmaf(v,w1.x,d[4]);  d[5]=fmaf(v,w1.y,d[5]);  d[6]=fmaf(v,w1.z,d[6]);  d[7]=fmaf(v,w1.w,d[7]);
    d[8]=fmaf(v,w2.x,d[8]);  d[9]=fmaf(v,w2.y,d[9]);  d[10]=fmaf(v,w2.z,d[10]); d[11]=fmaf(v,w2.w,d[11]);
    d[12]=fmaf(v,w3.x,d[12]); d[13]=fmaf(v,w3.y,d[13]); d[14]=fmaf(v,w3.z,d[14]); d[15]=fmaf(v,w3.w,d[15]);
    d[16]=fmaf(v,w4.x,d[16]); d[17]=fmaf(v,w4.y,d[17]); d[18]=fmaf(v,w4.z,d[18]); d[19]=fmaf(v,w4.w,d[19]);
    d[20]=fmaf(v,w5.x,d[20]); d[21]=fmaf(v,w5.y,d[21]); d[22]=fmaf(v,w5.z,d[22]); d[23]=fmaf(v,w5.w,d[23]);
    d[24]=fmaf(v,w6.x,d[24]); d[25]=fmaf(v,w6.y,d[25]); d[26]=fmaf(v,w6.z,d[26]);
  }
  float acc = 0.f;
  #pragma unroll
  for (int o=0;o<27;++o){
    int ci = o/9, r2 = (o - ci*9)/3, c2 = o%3;
    float tg = x[((b*3+ci)*32 + (oh+r2))*32 + (ow+c2)];
    float dv = 1.f/(1.f + __expf(-d[o]));
    float df = tg - dv;
    acc = fmaf(df, df, acc);
  }
  redbuf[t]=acc; __syncthreads();
  for (int off=128; off; off>>=1){ if (t<off) redbuf[t]+=redbuf[t+off]; __syncthreads(); }
  if (t==0) auxp[blockIdx.x] = redbuf[0];
}

// ---------------- A3: red -> packed x1p [pos][64], float4 gathers + fused bn1 stats ----------------
__global__ __launch_bounds__(256) void stage_a3p2(
    const float* __restrict__ svg_v, const unsigned char* __restrict__ svg_i,
    const float* __restrict__ redT, const float* __restrict__ red_b,
    u32* __restrict__ x1p, float* __restrict__ psum1, float* __restrict__ psq1)
{
  __shared__ __align__(16) float redl[256*68];  // 69632 B, row = 17 float4
  __shared__ u32   obuf[256*65];                // 66560 B
  const int t = threadIdx.x;
  for (int e=t; e<16384; e+=256) redl[(e>>6)*68 + (e&63)] = redT[e];
  __syncthreads();

  const int pos = blockIdx.x*256 + t;

  float v[32]; int a[32];
  #pragma unroll
  for (int j=0;j<32;++j) v[j] = svg_v[(size_t)j*230400 + pos];
  #pragma unroll
  for (int j=0;j<32;++j) a[j] = (int)svg_i[(size_t)j*230400 + pos]*17; // float4-row

  const float4* redl4 = (const float4*)redl;
  #pragma unroll 2
  for (int ocb=0; ocb<16; ++ocb){
    float s0 = red_b[4*ocb+0], s1 = red_b[4*ocb+1];
    float s2 = red_b[4*ocb+2], s3 = red_b[4*ocb+3];
    #pragma unroll
    for (int j=0;j<32;++j){
      float4 w = redl4[a[j] + ocb];
      s0 = fmaf(v[j], w.x, s0); s1 = fmaf(v[j], w.y, s1);
      s2 = fmaf(v[j], w.z, s2); s3 = fmaf(v[j], w.w, s3);
    }
    obuf[t*65 + 4*ocb+0] = packsplit(s0);
    obuf[t*65 + 4*ocb+1] = packsplit(s1);
    obuf[t*65 + 4*ocb+2] = packsplit(s2);
    obuf[t*65 + 4*ocb+3] = packsplit(s3);
  }
  __syncthreads();   // all redl reads + obuf writes complete

  const size_t base = (size_t)blockIdx.x*16384;
  float s = 0.f, q = 0.f;
  for (int e=t; e<16384; e+=256){
    u32 w = obuf[(e>>6)*65 + (e&63)];
    x1p[base + e] = w;
    float vv = unpackv(w);
    s += vv; q = fmaf(vv, vv, q);
  }
  float* ls = redl; float* lq = redl + 256;
  ls[t] = s; lq[t] = q; __syncthreads();
  if (t < 128){ ls[t] += ls[t+128]; lq[t] += lq[t+128]; } __syncthreads();
  if (t < 64){
    psum1[(size_t)blockIdx.x*64 + t] = ls[t] + ls[t+64];
    psq1 [(size_t)blockIdx.x*64 + t] = lq[t] + lq[t+64];
  }
}

// ---------------- bn1 finalize: one block per channel (64 blocks) ----------------
__global__ __launch_bounds__(256) void bn1_final(
    const float* __restrict__ ps, const float* __restrict__ pq,
    const float* __restrict__ g, const float* __restrict__ b2,
    float* __restrict__ sc, float* __restrict__ sh)
{
  __shared__ float ls[256], lq[256];
  const int c = blockIdx.x, t = threadIdx.x;
  float s=0.f, q=0.f;
  for (int i=t; i<900; i+=256){ s += ps[(size_t)i*64+c]; q += pq[(size_t)i*64+c]; }
  ls[t]=s; lq[t]=q; __syncthreads();
  for (int off=128; off; off>>=1){
    if (t<off){ ls[t]+=ls[t+off]; lq[t]+=lq[t+off]; } __syncthreads();
  }
  if (t==0){
    constexpr float inv_n = 1.f/230400.f;
    float m = ls[0]*inv_n;
    float var = fmaf(lq[0], inv_n, -m*m);
    float rs = rsqrtf(var + 1e-5f);
    float scale = g[c]*rs;
    sc[c] = scale;
    sh[c] = fmaf(-m, scale, b2[c]);
  }
}

// ---------------- generic BN finalize: ONE BLOCK PER CHANNEL ----------------
template<int C>
__global__ __launch_bounds__(256) void bn_finalG(
    const float* __restrict__ ps, const float* __restrict__ pq, int G,
    const float* __restrict__ g, const float* __restrict__ b2,
    float* __restrict__ sc, float* __restrict__ sh, float inv_n)
{
  __shared__ float ls[256], lq[256];
  const int c = blockIdx.x, t = threadIdx.x;
  float s=0.f, q=0.f;
  for (int i=t; i<G; i+=256){ s += ps[(size_t)i*C+c]; q += pq[(size_t)i*C+c]; }
  ls[t]=s; lq[t]=q; __syncthreads();
  for (int off=128; off; off>>=1){
    if (t<off){ ls[t]+=ls[t+off]; lq[t]+=lq[t+off]; } __syncthreads();
  }
  if (t==0){
    float m = ls[0]*inv_n;
    float var = fmaf(lq[0], inv_n, -m*m);
    float rs = rsqrtf(var + 1e-5f);
    float scale = g[c]*rs;
    sc[c] = scale;
    sh[c] = fmaf(-m, scale, b2[c]);
  }
}

// ---------------- cvt: in-place packed->packed BN+ReLU ----------------
template<int C>
__global__ void cvt_repack(u32* __restrict__ xp, const float* __restrict__ sc,
                           const float* __restrict__ sh, int total4){
  int i = blockIdx.x*256 + threadIdx.x;
  if (i >= total4) return;
  uint4* p = (uint4*)xp;
  uint4 w = p[i];
  int cb = (i*4) % C;     // C%4==0
  w.x = packsplit(fmaxf(fmaf(unpackv(w.x), sc[cb+0], sh[cb+0]), 0.f));
  w.y = packsplit(fmaxf(fmaf(unpackv(w.y), sc[cb+1], sh[cb+1]), 0.f));
  w.z = packsplit(fmaxf(fmaf(unpackv(w.z), sc[cb+2], sh[cb+2]), 0.f));
  w.w = packsplit(fmaxf(fmaf(unpackv(w.w), sc[cb+3], sh[cb+3]), 0.f));
  p[i] = w;
}

// ---------------- conv via MFMA implicit GEMM, 3x bf16 split + fused BN partial stats ----------------
template<int CIN,int COUT,int HIN,int WIN,int BM,int MW,bool POOL,bool PKOUT>
__global__ __launch_bounds__(256) void conv_mfma(
    const u32* __restrict__ xp, const u16* __restrict__ wh,
    const u16* __restrict__ wl, const float* __restrict__ bias,
    void* __restrict__ y_, float* __restrict__ psC, float* __restrict__ qsC)
{
  constexpr int HC=HIN-2, WC=WIN-2, TPI=CIN/32, KS=9*TPI, NCH=COUT/16;
  const int t = threadIdx.x, wid = t>>6, lane = t&63;
  const int p0 = blockIdx.x*BM;
  const int colg = lane>>4;
  const int col = lane&15;
  float* yf = (float*)y_;
  u32*   yp = (u32*)y_;

  const u32* Aptr[MW];
  #pragma unroll
  for (int m=0;m<MW;++m){
    int l = (wid*MW+m)*16 + col;
    int lc = l < BM ? l : BM-1;
    int p = p0 + lc;
    int b = p/(HC*WC); int rem = p - b*(HC*WC);
    int oh = rem/WC, ow = rem - (rem/WC)*WC;
    Aptr[m] = xp + ((size_t)((b*HIN+oh)*WIN+ow))*CIN + colg*8;
  }
  const size_t wb = (size_t)col*32 + colg*8;

  f32x4 acc[MW][NCH];
  #pragma unroll
  for (int m=0;m<MW;++m)
    #pragma unroll
    for (int nc=0;nc<NCH;++nc) acc[m][nc] = (f32x4){0.f,0.f,0.f,0.f};

  for (int ks=0; ks<KS; ++ks){
    const int tap = ks/TPI, cib = (ks - tap*TPI)*32;
    const int kh = tap/3, kw = tap - kh*3;
    short8v ah[MW], al[MW];
    #pragma unroll
    for (int m=0;m<MW;++m){
      const u32* ap = Aptr[m] + (kh*WIN + kw)*CIN + cib;
      uint4 qa = *(const uint4*)(ap);
      uint4 qb = *(const uint4*)(ap+4);
      ah[m][0]=(short)(qa.x&0xffffu); al[m][0]=(short)(qa.x>>16);
      ah[m][1]=(short)(qa.y&0xffffu); al[m][1]=(short)(qa.y>>16);
      ah[m][2]=(short)(qa.z&0xffffu); al[m][2]=(short)(qa.z>>16);
      ah[m][3]=(short)(qa.w&0xffffu); al[m][3]=(short)(qa.w>>16);
      ah[m][4]=(short)(qb.x&0xffffu); al[m][4]=(short)(qb.x>>16);
      ah[m][5]=(short)(qb.y&0xffffu); al[m][5]=(short)(qb.y>>16);
      ah[m][6]=(short)(qb.z&0xffffu); al[m][6]=(short)(qb.z>>16);
      ah[m][7]=(short)(qb.w&0xffffu); al[m][7]=(short)(qb.w>>16);
    }
    const u16* whp = wh + (size_t)ks*COUT*32 + wb;
    const u16* wlp = wl + (size_t)ks*COUT*32 + wb;
    #pragma unroll
    for (int nc=0;nc<NCH;++nc){
      short8v bh = *(const short8v*)(whp + nc*512);
      short8v bl = *(const short8v*)(wlp + nc*512);
      #pragma unroll
      for (int m=0;m<MW;++m){
        acc[m][nc] = __builtin_amdgcn_mfma_f32_16x16x32_bf16(ah[m], bh, acc[m][nc], 0,0,0);
        acc[m][nc] = __builtin_amdgcn_mfma_f32_16x16x32_bf16(ah[m], bl, acc[m][nc], 0,0,0);
        acc[m][nc] = __builtin_amdgcn_mfma_f32_16x16x32_bf16(al[m], bh, acc[m][nc], 0,0,0);
      }
    }
  }

  if constexpr (!POOL){
    __shared__ float ldsS[4][COUT], ldsQ[4][COUT];
    float sacc[NCH], qacc[NCH];
    #pragma unroll
    for (int nc=0;nc<NCH;++nc){ sacc[nc]=0.f; qacc[nc]=0.f; }
    #pragma unroll
    for (int m=0;m<MW;++m){
      const int lr0 = (wid*MW+m)*16 + colg*4;
      #pragma unroll
      for (int nc=0;nc<NCH;++nc){
        float bv = bias[nc*16+col];
        #pragma unroll
        for (int r=0;r<4;++r)
          if (lr0+r < BM){
            float ov = acc[m][nc][r] + bv;
            float vv;
            if constexpr (PKOUT){
              u32 w = packsplit(ov);
              yp[(size_t)(p0+lr0+r)*COUT + nc*16+col] = w;
              vv = unpackv(w);
            } else {
              yf[(size_t)(p0+lr0+r)*COUT + nc*16+col] = ov;
              vv = ov;
            }
            sacc[nc] += vv; qacc[nc] = fmaf(vv, vv, qacc[nc]);
          }
      }
    }
    #pragma unroll
    for (int nc=0;nc<NCH;++nc){
      float s_ = sacc[nc], q_ = qacc[nc];
      s_ += __shfl_xor(s_, 16); q_ += __shfl_xor(q_, 16);
      s_ += __shfl_xor(s_, 32); q_ += __shfl_xor(q_, 32);
      if (colg == 0){ ldsS[wid][nc*16+col] = s_; ldsQ[wid][nc*16+col] = q_; }
    }
    __syncthreads();
    if (t < COUT){
      psC[(size_t)blockIdx.x*COUT + t] = ldsS[0][t]+ldsS[1][t]+ldsS[2][t]+ldsS[3][t];
      qsC[(size_t)blockIdx.x*COUT + t] = ldsQ[0][t]+ldsQ[1][t]+ldsQ[2][t]+ldsQ[3][t];
    }
  } else {
    constexpr int LDC = COUT+4;
    __shared__ float lds[BM*LDC];
    #pragma unroll
    for (int m=0;m<MW;++m){
      const int lr0 = (wid*MW+m)*16 + colg*4;
      #pragma unroll
      for (int nc=0;nc<NCH;++nc){
        float bv = bias[nc*16+col];
        #pragma unroll
        for (int r=0;r<4;++r)
          if (lr0+r < BM) lds[(lr0+r)*LDC + nc*16+col] = acc[m][nc][r] + bv;
      }
    }
    __syncthreads();
    constexpr int WPO = WC/2;
    const size_t pbase = (size_t)p0/4;
    if (t < COUT){
      float s = 0.f, q = 0.f;
      for (int pl=0; pl<BM/4; ++pl){
        int poh = pl / WPO, pw = pl - poh*WPO;
        int r = (2*poh)*WC + 2*pw;
        float mx = fmaxf(fmaxf(lds[r*LDC+t],      lds[(r+1)*LDC+t]),
                         fmaxf(lds[(r+WC)*LDC+t], lds[(r+WC+1)*LDC+t]));
        float vv;
        if constexpr (PKOUT){
          u32 w = packsplit(mx);
          yp[(pbase + pl)*COUT + t] = w;
          vv = unpackv(w);
        } else {
          yf[(pbase + pl)*COUT + t] = mx;
          vv = mx;
        }
        s += vv; q = fmaf(vv, vv, q);
      }
      psC[(size_t)blockIdx.x*COUT + t] = s;
      qsC[(size_t)blockIdx.x*COUT + t] = q;
    }
  }
}

// ---------------- final: bnc + FC + argmax (+ aux reduce as extra block) ----------------
__global__ __launch_bounds__(256) void fc_kernel(
    const float* __restrict__ a5, const float* __restrict__ scale, const float* __restrict__ shift,
    const float* __restrict__ fcT, const float* __restrict__ fc_b,
    const float* __restrict__ auxp, float* __restrict__ outp)
{
  const int b = blockIdx.x, t = threadIdx.x;
  if (b == 256){   // aux-loss reduction block
    __shared__ float s[256];
    float a=0.f;
    for (int i=t; i<900; i+=256) a += auxp[i];
    s[t]=a; __syncthreads();
    for (int off=128; off; off>>=1){ if (t<off) s[t]+=s[t+off]; __syncthreads(); }
    if (t==0) outp[25856] = s[0] / 6220800.0f;
    return;
  }
  __shared__ float f[1024];
  __shared__ float part[256];
  __shared__ float lg[128];
  for (int e=t; e<1024; e+=256){
    int c = e & 255, hw = e >> 8;
    float v = a5[b*1024 + e];
    f[c*4 + hw] = fmaf(v, scale[c], shift[c]);
  }
  __syncthreads();
  const int o = t & 127, half = t >> 7;
  float s = 0.f;
  if (o < 100){
    const float* fp = f + half*512;
    const float* wp = fcT + half*512*100 + o;
    for (int j=0;j<512;++j) s = fmaf(fp[j], wp[j*100], s);
  }
  part[t] = s; __syncthreads();
  if (t < 128){
    float logit = part[t] + part[t+128] + ((t<100)? fc_b[t] : 0.f);
    lg[t] = (t<100)? logit : -3.0e38f;
    if (t<100) outp[b*100 + t] = logit;
  }
  __syncthreads();
  if (t==0){
    float m = lg[0]; int mi = 0;
    for (int i=1;i<100;++i){ if (lg[i] > m){ m = lg[i]; mi = i; } }
    outp[25600 + b] = (float)mi;
  }
}

// ---------------- launch ----------------
extern "C" void kernel_launch(void* const* d_in, const int* in_sizes, int n_in,
                              void* d_out, int out_size, void* d_ws, size_t ws_size,
                              hipStream_t stream)
{
  (void)in_sizes; (void)n_in; (void)out_size;
  const float* x     = (const float*)d_in[0];
  const float* enc_w = (const float*)d_in[1];
  const float* enc_b = (const float*)d_in[2];
  const float* dec_w = (const float*)d_in[3];
  const float* dec_b = (const float*)d_in[4];
  const float* red_w = (const float*)d_in[5];
  const float* red_b = (const float*)d_in[6];
  const float* bn1_g = (const float*)d_in[7];  const float* bn1_b = (const float*)d_in[8];
  const float* c1w   = (const float*)d_in[9];  const float* c1b   = (const float*)d_in[10];
  const float* bn2_g = (const float*)d_in[11]; const float* bn2_b = (const float*)d_in[12];
  const float* c2w   = (const float*)d_in[13]; const float* c2b   = (const float*)d_in[14];
  const float* bn3_g = (const float*)d_in[15]; const float* bn3_b = (const float*)d_in[16];
  const float* c3w   = (const float*)d_in[17]; const float* c3b   = (const float*)d_in[18];
  const float* bn4_g = (const float*)d_in[19]; const float* bn4_b = (const float*)d_in[20];
  const float* c4w   = (const float*)d_in[21]; const float* c4b   = (const float*)d_in[22];
  const float* bn5_g = (const float*)d_in[23]; const float* bn5_b = (const float*)d_in[24];
  const float* c5w   = (const float*)d_in[25]; const float* c5b   = (const float*)d_in[26];
  const float* bnc_g = (const float*)d_in[27]; const float* bnc_b = (const float*)d_in[28];
  const float* fc_w  = (const float*)d_in[29]; const float* fc_b  = (const float*)d_in[30];
  const int*   kp    = (const int*)d_in[31];
  float* out = (float*)d_out;
  float* ws  = (float*)d_ws;

  // ---- workspace layout (float slots) ----
  constexpr size_t OFF_ENCT = 0;
  constexpr size_t OFF_DECT = 7168;
  constexpr size_t OFF_REDT = 14336;
  constexpr size_t OFF_FCT  = 30720;
  constexpr size_t OFF_W1H = 133120, OFF_W1L = 160768;
  constexpr size_t OFF_W2H = 188416, OFF_W2L = 243712;
  constexpr size_t OFF_W3H = 299008, OFF_W3L = 391168;
  constexpr size_t OFF_W4H = 483328, OFF_W4L = 621568;
  constexpr size_t OFF_W5H = 759808, OFF_W5L = 980992;
  constexpr size_t OFF_SS1 = 1202176, OFF_SS2 = 1202304, OFF_SS3 = 1202496;
  constexpr size_t OFF_SS4 = 1202752, OFF_SS5 = 1203072, OFF_SSC = 1203456;
  constexpr size_t OFF_AUX  = 1302272;              // 900 aux
  constexpr size_t OFF_B    = 1303296;              // 14,745,600 (x1p | y2 | p4)
  constexpr size_t OFF_C    = 16048896;             // 9,216,000 (svv+svi | p1 | y3 | y5)
  constexpr size_t OFF_P1S  = 25264896;             // 57600 (bn1 partials, 900x64)
  constexpr size_t OFF_P1Q  = OFF_P1S + 57600;      // 57600
  constexpr size_t OFF_PCS  = OFF_P1Q + 57600;      // conv stats partials: max 1792*96
  constexpr size_t OFF_PCQ  = OFF_PCS + 172032;
  constexpr size_t TOTALF   = OFF_PCQ + 172032;     // ~103 MB
  if (ws_size < TOTALF*sizeof(float)) return;

  float* encTg = ws + OFF_ENCT;
  float* decT = ws + OFF_DECT; float* redT = ws + OFF_REDT; float* fcT = ws + OFF_FCT;
  u16* W1h = (u16*)(ws+OFF_W1H); u16* W1l = (u16*)(ws+OFF_W1L);
  u16* W2h = (u16*)(ws+OFF_W2H); u16* W2l = (u16*)(ws+OFF_W2L);
  u16* W3h = (u16*)(ws+OFF_W3H); u16* W3l = (u16*)(ws+OFF_W3L);
  u16* W4h = (u16*)(ws+OFF_W4H); u16* W4l = (u16*)(ws+OFF_W4L);
  u16* W5h = (u16*)(ws+OFF_W5H); u16* W5l = (u16*)(ws+OFF_W5L);
  float* ss1 = ws+OFF_SS1; float* ss2 = ws+OFF_SS2; float* ss3 = ws+OFF_SS3;
  float* ss4 = ws+OFF_SS4; float* ss5 = ws+OFF_SS5; float* ssc = ws+OFF_SSC;
  float* auxp = ws+OFF_AUX;
  float* psum1 = ws+OFF_P1S; float* psq1 = ws+OFF_P1Q;
  float* pcs = ws+OFF_PCS;  float* pcq = ws+OFF_PCQ;
  u32*   x1p = (u32*)(ws+OFF_B);
  u32*   y2p = (u32*)(ws+OFF_B);
  u32*   p4p = (u32*)(ws+OFF_B);
  float* svv = ws+OFF_C;
  unsigned char* svi = (unsigned char*)(ws+OFF_C+7372800);
  u32*   p1p = (u32*)(ws+OFF_C);
  u32*   y3p = (u32*)(ws+OFF_C);
  float* y5  = ws+OFF_C;

  prep_all<<<4694, 256, 0, stream>>>(enc_w, encTg, dec_w, decT, red_w, redT, fc_w, fcT,
                                     c1w, W1h, W1l, c2w, W2h, W2l, c3w, W3h, W3l,
                                     c4w, W4h, W4l, c5w, W5h, W5l);

  // stage A
  stage_a1<<<dim3(30,256), 256, 0, stream>>>(encTg, enc_b, x, kp, svv, svi);
  stage_a2<<<900, 256, 0, stream>>>(svv, svi, decT, dec_b, x, auxp);
  stage_a3p2<<<900, 256, 0, stream>>>(svv, svi, redT, red_b, x1p, psum1, psq1);

  // bn1: finalize from a3's fused partials (64 blocks), then in-place bn+relu repack
  bn1_final<<<64, 256, 0, stream>>>(psum1, psq1, bn1_g, bn1_b, ss1, ss1+64);
  cvt_repack<64><<<14400, 256, 0, stream>>>(x1p, ss1, ss1+64, 3686400);

  // conv1 (+fused pool + bn2 stats), MW=2, BM=112 -> PACKED p1
  conv_mfma<64,96,30,30,112,2,true,true><<<1792, 256, 0, stream>>>(x1p, W1h, W1l, c1b, p1p, pcs, pcq);
  bn_finalG<96><<<96, 256, 0, stream>>>(pcs, pcq, 1792, bn2_g, bn2_b, ss2, ss2+96, 1.f/50176.f);
  cvt_repack<96><<<(1204224+255)/256, 256, 0, stream>>>(p1p, ss2, ss2+96, 1204224);

  // conv2 (+bn3 stats), MW=3, BM=192 -> single CU-round (192 blocks)
  conv_mfma<96,128,14,14,192,3,false,true><<<192, 256, 0, stream>>>(p1p, W2h, W2l, c2b, y2p, pcs, pcq);
  bn_finalG<128><<<128, 256, 0, stream>>>(pcs, pcq, 192, bn3_g, bn3_b, ss3, ss3+128, 1.f/36864.f);
  cvt_repack<128><<<(1179648+255)/256, 256, 0, stream>>>(y2p, ss3, ss3+128, 1179648);

  // conv3 (+bn4 stats), MW=2, BM=128 -> PACKED y3
  conv_mfma<128,160,12,12,128,2,false,true><<<200, 256, 0, stream>>>(y2p, W3h, W3l, c3b, y3p, pcs, pcq);
  bn_finalG<160><<<160, 256, 0, stream>>>(pcs, pcq, 200, bn4_g, bn4_b, ss4, ss4+160, 1.f/25600.f);
  cvt_repack<160><<<(1024000+255)/256, 256, 0, stream>>>(y3p, ss4, ss4+160, 1024000);

  // conv4 (+fused pool + bn5 stats), MW=1 -> PACKED p4
  conv_mfma<160,192,10,10,64,1,true,true><<<256, 256, 0, stream>>>(y3p, W4h, W4l, c4b, p4p, pcs, pcq);
  bn_finalG<192><<<192, 256, 0, stream>>>(pcs, pcq, 256, bn5_g, bn5_b, ss5, ss5+192, 1.f/4096.f);
  cvt_repack<192><<<(196608+255)/256, 256, 0, stream>>>(p4p, ss5, ss5+192, 196608);

  // conv5 (+bnc stats), MW=1 -> f32 y5 (fc consumes f32 directly)
  conv_mfma<192,256,4,4,64,1,false,false><<<16, 256, 0, stream>>>(p4p, W5h, W5l, c5b, y5, pcs, pcq);
  bn_finalG<256><<<256, 256, 0, stream>>>(pcs, pcq, 16, bnc_g, bnc_b, ssc, ssc+256, 1.f/1024.f);
  fc_kernel<<<257, 256, 0, stream>>>(y5, ssc, ssc+256, fcT, fc_b, auxp, out);
}